// Round 6
// baseline (429.517 us; speedup 1.0000x reference)
//
#include <hip/hip_runtime.h>
#include <hip/hip_bf16.h>
#include <cstdint>
#include <cstddef>

// ---------------- types ----------------
typedef __attribute__((ext_vector_type(8))) short bf16x8;
typedef __attribute__((ext_vector_type(4))) float f32x4;

#define HDIM 1024
#define IDIM 2048
#define TTOK 4096
#define NEXP 8
#define ROWS_PAD 14336          // 256-padded routed (<=10240) + shared 4096
#define MT_MAX 64               // max 256-row m-tiles: <=40 routed + 16 shared
#define EXP_W_ELEMS 2097152ull  // 2048*1024 elems per weight matrix per expert

// ---------------- workspace layout (bytes) ----------------
#define OFF_HF   0ull                                            // [4096][1024] bf16
#define OFF_P    (OFF_HF + 4096ull * 1024ull * 2ull)             // [ROWS_PAD][2048] bf16
#define OFF_SLOT (OFF_P  + (size_t)ROWS_PAD * 2048ull * 2ull)    // [ROWS_PAD][1024] bf16
#define OFF_TOPI (OFF_SLOT + (size_t)ROWS_PAD * 1024ull * 2ull)  // [8192] int
#define OFF_TOPW (OFF_TOPI + 8192ull * 4ull)                     // [8192] f32
#define OFF_PROB (OFF_TOPW + 8192ull * 4ull)                     // [4096][8] f32
#define OFF_ZENT (OFF_PROB + 4096ull * 8ull * 4ull)              // [4096][2] f32
#define OFF_META (OFF_ZENT + 4096ull * 2ull * 4ull)              // ints, see below
#define OFF_LTOK (OFF_META + 4096ull)                            // [ROWS_PAD] int
#define OFF_LW   (OFF_LTOK + (size_t)ROWS_PAD * 4ull)            // [ROWS_PAD] f32
#define OFF_ROWS (OFF_LW + (size_t)ROWS_PAD * 4ull)              // [8192] int

// meta (ints): [0..8]=cnt, [16..24]=256-padded base, [32..40]=cursor,
//              [48]=ntiles256, [64..127]=tile->expert, [128..191]=tile->row0

#define VM_WAIT(n) asm volatile("s_waitcnt vmcnt(" #n ")" ::: "memory")
#define LGKM0 asm volatile("s_waitcnt lgkmcnt(0)" ::: "memory")
#define SBAR __builtin_amdgcn_s_barrier()
#define FENCE __builtin_amdgcn_sched_barrier(0)
#define PRIO_HI __builtin_amdgcn_s_setprio(1)
#define PRIO_LO __builtin_amdgcn_s_setprio(0)

__device__ __forceinline__ float clamp500(float v) {
  return fminf(fmaxf(v, -500.f), 500.f);
}

__device__ __forceinline__ unsigned short f2bf(float f) {
  unsigned int u = __float_as_uint(f);
  u += 0x7FFFu + ((u >> 16) & 1u);  // RNE; inputs always finite here
  return (unsigned short)(u >> 16);
}

__device__ __forceinline__ float bf2f(unsigned short u) {
  return __uint_as_float((unsigned)u << 16);
}

__device__ __forceinline__ unsigned pk2(float lo, float hi) {
  return (unsigned)f2bf(lo) | ((unsigned)f2bf(hi) << 16);
}

__device__ __forceinline__ uint4 pack4(float4 a, float4 b) {
  uint4 r;
  r.x = pk2(a.x, a.y); r.y = pk2(a.z, a.w);
  r.z = pk2(b.x, b.y); r.w = pk2(b.z, b.w);
  return r;
}

// async global->LDS, 16B per lane. LDS dest must be wave-uniform base + lane*16.
__device__ __forceinline__ void stage16(const unsigned short* g, unsigned short* l) {
  __builtin_amdgcn_global_load_lds(
      (const __attribute__((address_space(1))) void*)g,
      (__attribute__((address_space(3))) void*)l, 16, 0, 0);
}

__device__ __forceinline__ f32x4 mfma16(bf16x8 a, bf16x8 b, f32x4 c) {
  return __builtin_amdgcn_mfma_f32_16x16x32_bf16(a, b, c, 0, 0, 0);
}

// ---------------- router: LN -> logits -> softmax -> top2 + aux terms ----------------
__global__ __launch_bounds__(256) void router_kernel(
    const float* __restrict__ x, const float* __restrict__ lnw,
    const float* __restrict__ lnb, const float* __restrict__ rw,
    unsigned short* __restrict__ hf, int* __restrict__ top_i,
    float* __restrict__ top_w, float* __restrict__ probs_tok,
    float* __restrict__ zent) {
  int wv = threadIdx.x >> 6, lane = threadIdx.x & 63;
  int t = blockIdx.x * 4 + wv;  // one wave per token
  const float4* xr = (const float4*)(x + (size_t)t * HDIM);
  float4 v[4];
  float s = 0.f;
#pragma unroll
  for (int j = 0; j < 4; ++j) {
    float4 f = xr[j * 64 + lane];
    f.x = clamp500(f.x); f.y = clamp500(f.y);
    f.z = clamp500(f.z); f.w = clamp500(f.w);
    v[j] = f;
    ushort4 hh;
    hh.x = f2bf(f.x); hh.y = f2bf(f.y); hh.z = f2bf(f.z); hh.w = f2bf(f.w);
    ((ushort4*)hf)[(size_t)t * 256 + j * 64 + lane] = hh;
    s += f.x + f.y + f.z + f.w;
  }
#pragma unroll
  for (int m = 32; m; m >>= 1) s += __shfl_xor(s, m);
  float mu = s * (1.f / HDIM);
  float s2 = 0.f;
#pragma unroll
  for (int j = 0; j < 4; ++j) {
    float4 d = v[j];
    d.x -= mu; d.y -= mu; d.z -= mu; d.w -= mu;
    s2 += d.x * d.x + d.y * d.y + d.z * d.z + d.w * d.w;
  }
#pragma unroll
  for (int m = 32; m; m >>= 1) s2 += __shfl_xor(s2, m);
  float rstd = rsqrtf(s2 * (1.f / HDIM) + 1e-5f);
  float acc[8];
#pragma unroll
  for (int e = 0; e < 8; ++e) acc[e] = 0.f;
#pragma unroll
  for (int j = 0; j < 4; ++j) {
    float4 w = ((const float4*)lnw)[j * 64 + lane];
    float4 b = ((const float4*)lnb)[j * 64 + lane];
    float4 hn;
    hn.x = fminf(fmaxf((v[j].x - mu) * rstd * w.x + b.x, -50.f), 50.f);
    hn.y = fminf(fmaxf((v[j].y - mu) * rstd * w.y + b.y, -50.f), 50.f);
    hn.z = fminf(fmaxf((v[j].z - mu) * rstd * w.z + b.z, -50.f), 50.f);
    hn.w = fminf(fmaxf((v[j].w - mu) * rstd * w.w + b.w, -50.f), 50.f);
#pragma unroll
    for (int e = 0; e < 8; ++e) {
      float4 r = ((const float4*)(rw + e * HDIM))[j * 64 + lane];
      acc[e] += hn.x * r.x + hn.y * r.y + hn.z * r.z + hn.w * r.w;
    }
  }
#pragma unroll
  for (int e = 0; e < 8; ++e) {
    float a = acc[e];
#pragma unroll
    for (int m = 32; m; m >>= 1) a += __shfl_xor(a, m);
    acc[e] = a;
  }
  if (lane == 0) {
    float lg[8], mx = -1e30f;
#pragma unroll
    for (int e = 0; e < 8; ++e) {
      float l = fminf(fmaxf(acc[e], -10.f), 10.f);
      lg[e] = l;
      mx = fmaxf(mx, l);
    }
    float se = 0.f;
    float ex[8];
#pragma unroll
    for (int e = 0; e < 8; ++e) { ex[e] = expf(lg[e] - mx); se += ex[e]; }
    float inv = 1.f / se;
    float pr[8];
#pragma unroll
    for (int e = 0; e < 8; ++e) {
      float p = ex[e] * inv;
      pr[e] = fminf(fmaxf(p, 1e-4f), 1.f);
      probs_tok[t * 8 + e] = pr[e];
    }
    int i0 = 0; float v0 = pr[0];
#pragma unroll
    for (int e = 1; e < 8; ++e) if (pr[e] > v0) { v0 = pr[e]; i0 = e; }
    int i1 = -1; float v1 = -1.f;
#pragma unroll
    for (int e = 0; e < 8; ++e) if (e != i0 && pr[e] > v1) { v1 = pr[e]; i1 = e; }
    float dsum = fmaxf(v0 + v1, 1e-4f);
    top_i[2 * t] = i0; top_i[2 * t + 1] = i1;
    top_w[2 * t] = v0 / dsum; top_w[2 * t + 1] = v1 / dsum;
    float lse = mx + logf(se);
    zent[2 * t] = lse * lse;
    float ent = 0.f;
#pragma unroll
    for (int e = 0; e < 8; ++e) {
      float ps = fminf(fmaxf(pr[e], 1e-4f), 1.f - 1e-4f);
      ent -= ps * logf(ps);
    }
    zent[2 * t + 1] = ent;
  }
}

// ---------------- aux loss + 256-padded tile map (single block, deterministic) ----------------
__global__ __launch_bounds__(256) void aux_kernel(
    const int* __restrict__ top_i, const float* __restrict__ probs_tok,
    const float* __restrict__ zent, int* __restrict__ meta,
    int* __restrict__ ltok, float* __restrict__ lw,
    float* __restrict__ aux_out) {
  __shared__ int sc[8];
  __shared__ float red[256];
  __shared__ float sums[10];
  int tid = threadIdx.x;
  if (tid < 8) sc[tid] = 0;
  __syncthreads();
  for (int s = tid; s < 8192; s += 256) atomicAdd(&sc[top_i[s]], 1);
  // default-init padded token lists (scatter overwrites the live ones)
  for (int i = tid; i < ROWS_PAD; i += 256) { ltok[i] = 0; lw[i] = 0.f; }
  float pe[8] = {0, 0, 0, 0, 0, 0, 0, 0};
  float zs = 0.f, es = 0.f;
  for (int t = tid; t < 4096; t += 256) {
#pragma unroll
    for (int e = 0; e < 8; ++e) pe[e] += probs_tok[t * 8 + e];
    zs += zent[2 * t];
    es += zent[2 * t + 1];
  }
  for (int e = 0; e < 10; ++e) {
    float val = (e < 8) ? pe[e] : ((e == 8) ? zs : es);
    red[tid] = val;
    __syncthreads();
    for (int off = 128; off; off >>= 1) {
      if (tid < off) red[tid] += red[tid + off];
      __syncthreads();
    }
    if (tid == 0) sums[e] = red[0];
    __syncthreads();
  }
  if (tid == 0) {
    float lb = 0.f, usage = 0.f;
    for (int e = 0; e < 8; ++e) {
      float tpe = (float)sc[e] / 8192.f;
      float avg = sums[e] / 4096.f;
      lb += tpe * avg;
      usage += (tpe > 0.01f) ? 1.f : 0.f;
    }
    lb *= 8.f;
    float z_loss = (sums[8] / 4096.f) * 0.001f;
    float ent_loss = fmaxf(logf(8.f) - sums[9] / 4096.f, 0.f) * 0.01f;
    float util = (1.f - usage / 8.f) * 0.1f;
    float aux = fminf(fmaxf(lb + z_loss + ent_loss + util, 0.f), 10.f);
    *aux_out = aux;
    // 256-padded tile map
    int base = 0, tct = 0;
    for (int e = 0; e < 8; ++e) {
      int cnt = sc[e];
      meta[e] = cnt;
      meta[16 + e] = base;
      meta[32 + e] = 0;
      int nt = (cnt + 255) >> 8;
      for (int i = 0; i < nt; ++i) { meta[64 + tct] = e; meta[128 + tct] = base + i * 256; ++tct; }
      base += nt * 256;
    }
    meta[8] = TTOK;           // shared "expert"
    meta[16 + 8] = base;      // shared padded base
    meta[32 + 8] = 0;
    for (int i = 0; i < 16; ++i) { meta[64 + tct] = 8; meta[128 + tct] = base + i * 256; ++tct; }
    meta[48] = tct;
  }
}

// ---------------- scatter tokens into per-expert padded lists ----------------
__global__ __launch_bounds__(256) void scatter_kernel(
    const int* __restrict__ top_i, const float* __restrict__ top_w,
    int* __restrict__ meta, int* __restrict__ ltok, float* __restrict__ lw,
    int* __restrict__ rowslot) {
  int s = blockIdx.x * 256 + threadIdx.x;
  if (s < 8192) {
    int e = top_i[s];
    int pos = atomicAdd(&meta[32 + e], 1);
    int idx = meta[16 + e] + pos;
    ltok[idx] = s >> 1;
    lw[idx] = top_w[s];
    rowslot[s] = idx;
  }
  if (s < TTOK) {  // identity list for shared expert
    int sb = meta[16 + 8];
    ltok[sb + s] = s;
    lw[sb + s] = 1.f;
  }
}

// ---------------- GEMM1: P = clamp(silu(clamp(A*Wg^T)) * clamp(A*Wu^T)) ----------------
// BM=256, BN=128 (G and U), BK=64, 8 waves (2x4). A (bf16) via global_load_lds;
// weights read DIRECTLY as fp32 and reg-staged. T14 discipline: ALL loads
// (A-stages + 8 weight float4s) issued at iteration TOP; ALL commits
// (pack + swizzled ds_write) AFTER kk1, fenced so no wait lands inside the
// MFMA clusters. One vmcnt(0)+lgkmcnt(0)+barrier per iteration.
__global__ __launch_bounds__(512, 1) void gemm1_kernel(
    const unsigned short* __restrict__ hf,
    const float* __restrict__ wg_all, const float* __restrict__ wu_all,
    const float* __restrict__ swg, const float* __restrict__ swu,
    unsigned short* __restrict__ P,
    const int* __restrict__ meta, const int* __restrict__ ltok) {
  int mt = blockIdx.y, nt = blockIdx.x;
  if (mt >= meta[48]) return;
  int ex = meta[64 + mt];
  int r0 = meta[128 + mt];
  extern __shared__ unsigned short lds[];
  unsigned short* sA = lds;          // 2 x 16384 elems (256x64)
  unsigned short* sG = lds + 32768;  // 2 x 8192  (128x64)
  unsigned short* sU = lds + 49152;  // 2 x 8192
  int tid = threadIdx.x, lane = tid & 63, wv = tid >> 6;
  int wr = wv >> 2, wc = wv & 3;
  int l15 = lane & 15, l4 = lane >> 4;
  int srow = tid >> 3;              // A staging row within a 64-row issue
  int gch = (tid & 7) ^ (srow & 7); // inverse-swizzled A source 16B chunk
  int ldst = tid * 8;               // linear LDS dest elems within an issue
  const float* wg = (ex == 8) ? swg : wg_all + (size_t)ex * EXP_W_ELEMS;
  const float* wu = (ex == 8) ? swu : wu_all + (size_t)ex * EXP_W_ELEMS;
  int n0 = nt * 128;
  const unsigned short* srcA[4];
#pragma unroll
  for (int i = 0; i < 4; ++i) {
    int tok = ltok[r0 + i * 64 + srow];
    srcA[i] = hf + (size_t)tok * HDIM + gch * 8;
  }
  // weight reg-staging geometry: [128 rows][64 k-floats]; 512 thr -> 16 floats each
  int wrow = tid >> 2;            // 0..127
  int wc0 = (tid & 3) * 2;        // first of 2 owned 8-elem chunks
  const float* gsrc = wg + (size_t)(n0 + wrow) * HDIM + wc0 * 8;
  const float* usrc = wu + (size_t)(n0 + wrow) * HDIM + wc0 * 8;
  int wdst0 = wrow * 64 + ((wc0) ^ (wrow & 7)) * 8;
  int wdst1 = wrow * 64 + ((wc0 + 1) ^ (wrow & 7)) * 8;
  // swizzled ds_read chunk per kk (row&7 == lane&7 for all frag rows)
  int ch0 = (0 + l4) ^ (lane & 7);
  int ch1 = (4 + l4) ^ (lane & 7);
  int baseA = (wr * 128 + l15) * 64;
  int baseG = (wc * 32 + l15) * 64;

  f32x4 zero = {0.f, 0.f, 0.f, 0.f};
  f32x4 accg[8][2], accu[8][2];
#pragma unroll
  for (int m = 0; m < 8; ++m)
#pragma unroll
    for (int n = 0; n < 2; ++n) { accg[m][n] = zero; accu[m][n] = zero; }

  // prologue: fill buf0
#pragma unroll
  for (int i = 0; i < 4; ++i) stage16(srcA[i], &sA[i * 4096 + ldst]);
  {
    float4 g0 = *(const float4*)(gsrc);
    float4 g1 = *(const float4*)(gsrc + 4);
    float4 g2 = *(const float4*)(gsrc + 8);
    float4 g3 = *(const float4*)(gsrc + 12);
    float4 u0 = *(const float4*)(usrc);
    float4 u1 = *(const float4*)(usrc + 4);
    float4 u2 = *(const float4*)(usrc + 8);
    float4 u3 = *(const float4*)(usrc + 12);
    *(uint4*)&sG[wdst0] = pack4(g0, g1);
    *(uint4*)&sG[wdst1] = pack4(g2, g3);
    *(uint4*)&sU[wdst0] = pack4(u0, u1);
    *(uint4*)&sU[wdst1] = pack4(u2, u3);
  }
  VM_WAIT(0);
  LGKM0;
  SBAR;

  for (int t = 0; t < 16; ++t) {
    int cur = t & 1, nxt = cur ^ 1;
    int cbA = cur * 16384, cbG = cur * 8192;
    int nbA = nxt * 16384, nbG = nxt * 8192;
    bool pre = (t < 15);
    int k1 = (t + 1) * 64;
    float4 g0, g1, g2, g3, u0, u1, u2, u3;
    // ---- iteration top: issue EVERYTHING for t+1 ----
    if (pre) {
      stage16(srcA[0] + k1, &sA[nbA + 0 * 4096 + ldst]);
      stage16(srcA[1] + k1, &sA[nbA + 1 * 4096 + ldst]);
      stage16(srcA[2] + k1, &sA[nbA + 2 * 4096 + ldst]);
      stage16(srcA[3] + k1, &sA[nbA + 3 * 4096 + ldst]);
      g0 = *(const float4*)(gsrc + k1);
      g1 = *(const float4*)(gsrc + k1 + 4);
      g2 = *(const float4*)(gsrc + k1 + 8);
      g3 = *(const float4*)(gsrc + k1 + 12);
      u0 = *(const float4*)(usrc + k1);
      u1 = *(const float4*)(usrc + k1 + 4);
      u2 = *(const float4*)(usrc + k1 + 8);
      u3 = *(const float4*)(usrc + k1 + 12);
    }
    FENCE;  // pin loads at top (no sinking toward their commit)
    bf16x8 af0[8], af1[8], gf0[2], gf1[2], uf0[2], uf1[2];
    // ---- kk0 ----
#pragma unroll
    for (int m = 0; m < 8; ++m)
      af0[m] = *(const bf16x8*)&sA[cbA + baseA + m * 1024 + ch0 * 8];
#pragma unroll
    for (int n = 0; n < 2; ++n)
      gf0[n] = *(const bf16x8*)&sG[cbG + baseG + n * 1024 + ch0 * 8];
    PRIO_HI;
#pragma unroll
    for (int m = 0; m < 8; ++m)
#pragma unroll
      for (int n = 0; n < 2; ++n)
        accg[m][n] = mfma16(af0[m], gf0[n], accg[m][n]);
    PRIO_LO;
#pragma unroll
    for (int n = 0; n < 2; ++n)
      uf0[n] = *(const bf16x8*)&sU[cbG + baseG + n * 1024 + ch0 * 8];
    PRIO_HI;
#pragma unroll
    for (int m = 0; m < 8; ++m)
#pragma unroll
      for (int n = 0; n < 2; ++n)
        accu[m][n] = mfma16(af0[m], uf0[n], accu[m][n]);
    PRIO_LO;
    // ---- kk1 ----
#pragma unroll
    for (int m = 0; m < 8; ++m)
      af1[m] = *(const bf16x8*)&sA[cbA + baseA + m * 1024 + ch1 * 8];
#pragma unroll
    for (int n = 0; n < 2; ++n)
      gf1[n] = *(const bf16x8*)&sG[cbG + baseG + n * 1024 + ch1 * 8];
    PRIO_HI;
#pragma unroll
    for (int m = 0; m < 8; ++m)
#pragma unroll
      for (int n = 0; n < 2; ++n)
        accg[m][n] = mfma16(af1[m], gf1[n], accg[m][n]);
    PRIO_LO;
#pragma unroll
    for (int n = 0; n < 2; ++n)
      uf1[n] = *(const bf16x8*)&sU[cbG + baseG + n * 1024 + ch1 * 8];
    PRIO_HI;
#pragma unroll
    for (int m = 0; m < 8; ++m)
#pragma unroll
      for (int n = 0; n < 2; ++n)
        accu[m][n] = mfma16(af1[m], uf1[n], accu[m][n]);
    PRIO_LO;
    FENCE;  // commit (and its waits) stay BELOW both MFMA clusters
    // ---- iteration bottom: commit weights for t+1 ----
    if (pre) {
      *(uint4*)&sG[nbG + wdst0] = pack4(g0, g1);
      *(uint4*)&sG[nbG + wdst1] = pack4(g2, g3);
      *(uint4*)&sU[nbG + wdst0] = pack4(u0, u1);
      *(uint4*)&sU[nbG + wdst1] = pack4(u2, u3);
    }
    VM_WAIT(0);   // this iter's A-stages (issued a full compute phase ago)
    LGKM0;        // ds_writes to nxt complete
    SBAR;
  }
  // epilogue: SwiGLU, write bf16 P (padded rows junk, never read)
  int rbase = r0 + wr * 128 + l4 * 4;
  int cbase = n0 + wc * 32 + l15;
#pragma unroll
  for (int m = 0; m < 8; ++m) {
#pragma unroll
    for (int r = 0; r < 4; ++r) {
      size_t prow = (size_t)(rbase + m * 16 + r) * IDIM;
#pragma unroll
      for (int n = 0; n < 2; ++n) {
        float g = clamp500(accg[m][n][r]);
        float u = clamp500(accu[m][n][r]);
        float sl = g / (1.f + __expf(-g));
        float p = clamp500(sl * u);
        P[prow + cbase + n * 16] = f2bf(p);
      }
    }
  }
}

// ---------------- GEMM2: slot = weight * clamp(P*Wd^T)  (shared: clamp(clamp(.)*sig)) ----------------
// BM=256, BN=256, BK=64, 8 waves. A (P, bf16) via global_load_lds; wd read as
// fp32, reg-staged. Same all-loads-at-top / all-commits-at-bottom schedule.
__global__ __launch_bounds__(512, 1) void gemm2_kernel(
    const unsigned short* __restrict__ P,
    const float* __restrict__ wd_all, const float* __restrict__ swd,
    unsigned short* __restrict__ slot,
    const int* __restrict__ meta, const float* __restrict__ lw,
    const float* __restrict__ sgate) {
  int mt = blockIdx.y, nt = blockIdx.x;
  if (mt >= meta[48]) return;
  int ex = meta[64 + mt];
  int r0 = meta[128 + mt];
  extern __shared__ unsigned short lds[];
  unsigned short* sA = lds;          // 2 x 16384 (256x64)
  unsigned short* sB = lds + 32768;  // 2 x 16384 (256x64)
  int tid = threadIdx.x, lane = tid & 63, wv = tid >> 6;
  int wr = wv >> 2, wc = wv & 3;
  int l15 = lane & 15, l4 = lane >> 4;
  int srow = tid >> 3;
  int gch = (tid & 7) ^ (srow & 7);
  int ldst = tid * 8;
  const float* wd = (ex == 8) ? swd : wd_all + (size_t)ex * EXP_W_ELEMS;
  int n0 = nt * 256;
  const unsigned short* srcA[4];
#pragma unroll
  for (int i = 0; i < 4; ++i)
    srcA[i] = P + (size_t)(r0 + i * 64 + srow) * IDIM + gch * 8;
  // weight staging: [256 rows][64 k-floats]; 512 thr -> 32 floats each
  int wrow = tid >> 1;            // 0..255
  int wc0 = (tid & 1) * 4;        // first of 4 owned chunks
  const float* bsrc = wd + (size_t)(n0 + wrow) * IDIM + wc0 * 8;
  int wdst0 = wrow * 64 + ((wc0) ^ (wrow & 7)) * 8;
  int wdst1 = wrow * 64 + ((wc0 + 1) ^ (wrow & 7)) * 8;
  int wdst2 = wrow * 64 + ((wc0 + 2) ^ (wrow & 7)) * 8;
  int wdst3 = wrow * 64 + ((wc0 + 3) ^ (wrow & 7)) * 8;
  int ch0 = (0 + l4) ^ (lane & 7);
  int ch1 = (4 + l4) ^ (lane & 7);
  int baseA = (wr * 128 + l15) * 64;
  int baseB = (wc * 64 + l15) * 64;

  f32x4 zero = {0.f, 0.f, 0.f, 0.f};
  f32x4 acc[8][4];
#pragma unroll
  for (int m = 0; m < 8; ++m)
#pragma unroll
    for (int n = 0; n < 4; ++n) acc[m][n] = zero;

  // prologue
#pragma unroll
  for (int i = 0; i < 4; ++i) stage16(srcA[i], &sA[i * 4096 + ldst]);
  {
    float4 b0 = *(const float4*)(bsrc);
    float4 b1 = *(const float4*)(bsrc + 4);
    float4 b2 = *(const float4*)(bsrc + 8);
    float4 b3 = *(const float4*)(bsrc + 12);
    float4 b4 = *(const float4*)(bsrc + 16);
    float4 b5 = *(const float4*)(bsrc + 20);
    float4 b6 = *(const float4*)(bsrc + 24);
    float4 b7 = *(const float4*)(bsrc + 28);
    *(uint4*)&sB[wdst0] = pack4(b0, b1);
    *(uint4*)&sB[wdst1] = pack4(b2, b3);
    *(uint4*)&sB[wdst2] = pack4(b4, b5);
    *(uint4*)&sB[wdst3] = pack4(b6, b7);
  }
  VM_WAIT(0);
  LGKM0;
  SBAR;

  for (int t = 0; t < 32; ++t) {
    int cur = t & 1, nxt = cur ^ 1;
    int cb = cur * 16384, nb = nxt * 16384;
    bool pre = (t < 31);
    int k1 = (t + 1) * 64;
    float4 b0, b1, b2, b3, b4, b5, b6, b7;
    // ---- iteration top: issue EVERYTHING for t+1 ----
    if (pre) {
      stage16(srcA[0] + k1, &sA[nb + 0 * 4096 + ldst]);
      stage16(srcA[1] + k1, &sA[nb + 1 * 4096 + ldst]);
      stage16(srcA[2] + k1, &sA[nb + 2 * 4096 + ldst]);
      stage16(srcA[3] + k1, &sA[nb + 3 * 4096 + ldst]);
      b0 = *(const float4*)(bsrc + k1);
      b1 = *(const float4*)(bsrc + k1 + 4);
      b2 = *(const float4*)(bsrc + k1 + 8);
      b3 = *(const float4*)(bsrc + k1 + 12);
      b4 = *(const float4*)(bsrc + k1 + 16);
      b5 = *(const float4*)(bsrc + k1 + 20);
      b6 = *(const float4*)(bsrc + k1 + 24);
      b7 = *(const float4*)(bsrc + k1 + 28);
    }
    FENCE;
    bf16x8 af0[8], af1[8], bf0[4], bf1[4];
    // ---- kk0 ----
#pragma unroll
    for (int m = 0; m < 8; ++m)
      af0[m] = *(const bf16x8*)&sA[cb + baseA + m * 1024 + ch0 * 8];
#pragma unroll
    for (int n = 0; n < 4; ++n)
      bf0[n] = *(const bf16x8*)&sB[cb + baseB + n * 1024 + ch0 * 8];
    PRIO_HI;
#pragma unroll
    for (int m = 0; m < 8; ++m)
#pragma unroll
      for (int n = 0; n < 4; ++n)
        acc[m][n] = mfma16(af0[m], bf0[n], acc[m][n]);
    PRIO_LO;
    // ---- kk1 ----
#pragma unroll
    for (int m = 0; m < 8; ++m)
      af1[m] = *(const bf16x8*)&sA[cb + baseA + m * 1024 + ch1 * 8];
#pragma unroll
    for (int n = 0; n < 4; ++n)
      bf1[n] = *(const bf16x8*)&sB[cb + baseB + n * 1024 + ch1 * 8];
    PRIO_HI;
#pragma unroll
    for (int m = 0; m < 8; ++m)
#pragma unroll
      for (int n = 0; n < 4; ++n)
        acc[m][n] = mfma16(af1[m], bf1[n], acc[m][n]);
    PRIO_LO;
    FENCE;
    // ---- iteration bottom: commit weights for t+1 ----
    if (pre) {
      *(uint4*)&sB[nb + wdst0] = pack4(b0, b1);
      *(uint4*)&sB[nb + wdst1] = pack4(b2, b3);
      *(uint4*)&sB[nb + wdst2] = pack4(b4, b5);
      *(uint4*)&sB[nb + wdst3] = pack4(b6, b7);
    }
    VM_WAIT(0);
    LGKM0;
    SBAR;
  }
  float gsig = 1.f / (1.f + __expf(-sgate[0]));
  int rbase = r0 + wr * 128 + l4 * 4;
  int cbase = n0 + wc * 64 + l15;
#pragma unroll
  for (int m = 0; m < 8; ++m) {
#pragma unroll
    for (int r = 0; r < 4; ++r) {
      int row = rbase + m * 16 + r;
      float wgt = (ex == 8) ? 1.f : lw[row];
      size_t srow_o = (size_t)row * HDIM;
#pragma unroll
      for (int n = 0; n < 4; ++n) {
        float o = clamp500(acc[m][n][r]);
        float val = (ex == 8) ? clamp500(o * gsig) : wgt * o;
        slot[srow_o + cbase + n * 16] = f2bf(val);
      }
    }
  }
}

// ---------------- combine: final = clamp(slot0 + slot1 + shared) ----------------
__global__ __launch_bounds__(256) void combine_kernel(
    const unsigned short* __restrict__ slot, const int* __restrict__ rowslot,
    const int* __restrict__ meta, float* __restrict__ out) {
  int i = blockIdx.x * 256 + threadIdx.x;  // 4-elem group index
  int t = i >> 8;
  int c = (i & 255) * 4;
  int sb = meta[16 + 8];
  int r0 = rowslot[2 * t], r1 = rowslot[2 * t + 1];
  ushort4 va = *(const ushort4*)(slot + (size_t)r0 * HDIM + c);
  ushort4 vb = *(const ushort4*)(slot + (size_t)r1 * HDIM + c);
  ushort4 vs = *(const ushort4*)(slot + (size_t)(sb + t) * HDIM + c);
  float4 o;
  o.x = clamp500(bf2f(va.x) + bf2f(vb.x) + bf2f(vs.x));
  o.y = clamp500(bf2f(va.y) + bf2f(vb.y) + bf2f(vs.y));
  o.z = clamp500(bf2f(va.z) + bf2f(vb.z) + bf2f(vs.z));
  o.w = clamp500(bf2f(va.w) + bf2f(vb.w) + bf2f(vs.w));
  *(float4*)(out + (size_t)t * HDIM + c) = o;
}

// ---------------- launch ----------------
extern "C" void kernel_launch(void* const* d_in, const int* in_sizes, int n_in,
                              void* d_out, int out_size, void* d_ws, size_t ws_size,
                              hipStream_t stream) {
  const float* x     = (const float*)d_in[0];
  const float* lnw   = (const float*)d_in[1];
  const float* lnb   = (const float*)d_in[2];
  const float* rw    = (const float*)d_in[3];
  const float* wg_f  = (const float*)d_in[4];
  const float* wu_f  = (const float*)d_in[5];
  const float* wd_f  = (const float*)d_in[6];
  const float* swg_f = (const float*)d_in[7];
  const float* swu_f = (const float*)d_in[8];
  const float* swd_f = (const float*)d_in[9];
  const float* sgate = (const float*)d_in[10];
  float* out = (float*)d_out;

  char* ws = (char*)d_ws;
  unsigned short* hf  = (unsigned short*)(ws + OFF_HF);
  unsigned short* P   = (unsigned short*)(ws + OFF_P);
  unsigned short* slot = (unsigned short*)(ws + OFF_SLOT);
  int*   top_i   = (int*)(ws + OFF_TOPI);
  float* top_w   = (float*)(ws + OFF_TOPW);
  float* probs   = (float*)(ws + OFF_PROB);
  float* zent    = (float*)(ws + OFF_ZENT);
  int*   meta    = (int*)(ws + OFF_META);
  int*   ltok    = (int*)(ws + OFF_LTOK);
  float* lw      = (float*)(ws + OFF_LW);
  int*   rowslot = (int*)(ws + OFF_ROWS);

  hipFuncSetAttribute((const void*)gemm1_kernel,
                      hipFuncAttributeMaxDynamicSharedMemorySize, 131072);
  hipFuncSetAttribute((const void*)gemm2_kernel,
                      hipFuncAttributeMaxDynamicSharedMemorySize, 131072);

  router_kernel<<<TTOK / 4, 256, 0, stream>>>(x, lnw, lnb, rw, hf, top_i, top_w, probs, zent);
  aux_kernel<<<1, 256, 0, stream>>>(top_i, probs, zent, meta, ltok, lw, out + (size_t)TTOK * HDIM);
  scatter_kernel<<<32, 256, 0, stream>>>(top_i, top_w, meta, ltok, lw, rowslot);

  gemm1_kernel<<<dim3(16, MT_MAX), 512, 131072, stream>>>(
      hf, wg_f, wu_f, swg_f, swu_f, P, meta, ltok);
  gemm2_kernel<<<dim3(4, MT_MAX), 512, 131072, stream>>>(
      P, wd_f, swd_f, slot, meta, lw, sgate);
  combine_kernel<<<TTOK * HDIM / 4 / 256, 256, 0, stream>>>(slot, rowslot, meta, out);
}

// Round 7
// 391.267 us; speedup vs baseline: 1.0978x; 1.0978x over previous
//
#include <hip/hip_runtime.h>
#include <hip/hip_bf16.h>
#include <cstdint>
#include <cstddef>

// ---------------- types ----------------
typedef __attribute__((ext_vector_type(8))) short bf16x8;
typedef __attribute__((ext_vector_type(4))) float f32x4;

#define HDIM 1024
#define IDIM 2048
#define TTOK 4096
#define NEXP 8
#define ROWS_PAD 14336          // 256-padded routed (<=10240) + shared 4096
#define MT_MAX 64               // max 256-row m-tiles: <=40 routed + 16 shared
#define EXP_W_ELEMS 2097152ull  // 2048*1024 elems per weight matrix per expert

// ---------------- workspace layout (bytes) ----------------
#define OFF_HF   0ull                                            // [4096][1024] bf16
#define OFF_P    (OFF_HF + 4096ull * 1024ull * 2ull)             // [ROWS_PAD][2048] bf16
#define OFF_SLOT (OFF_P  + (size_t)ROWS_PAD * 2048ull * 2ull)    // [ROWS_PAD][1024] bf16
#define OFF_TOPI (OFF_SLOT + (size_t)ROWS_PAD * 1024ull * 2ull)  // [8192] int
#define OFF_TOPW (OFF_TOPI + 8192ull * 4ull)                     // [8192] f32
#define OFF_PROB (OFF_TOPW + 8192ull * 4ull)                     // [4096][8] f32
#define OFF_ZENT (OFF_PROB + 4096ull * 8ull * 4ull)              // [4096][2] f32
#define OFF_META (OFF_ZENT + 4096ull * 2ull * 4ull)              // ints, see below
#define OFF_LTOK (OFF_META + 4096ull)                            // [ROWS_PAD] int
#define OFF_LW   (OFF_LTOK + (size_t)ROWS_PAD * 4ull)            // [ROWS_PAD] f32
#define OFF_ROWS (OFF_LW + (size_t)ROWS_PAD * 4ull)              // [8192] int

// meta (ints): [0..8]=cnt, [16..24]=256-padded base, [32..40]=cursor,
//              [48]=ntiles256, [64..127]=tile->expert, [128..191]=tile->row0

#define VM_WAIT(n) asm volatile("s_waitcnt vmcnt(" #n ")" ::: "memory")
#define LGKM0 asm volatile("s_waitcnt lgkmcnt(0)" ::: "memory")
#define SBAR __builtin_amdgcn_s_barrier()
#define FENCE __builtin_amdgcn_sched_barrier(0)
#define PRIO_HI __builtin_amdgcn_s_setprio(1)
#define PRIO_LO __builtin_amdgcn_s_setprio(0)

__device__ __forceinline__ float clamp500(float v) {
  return fminf(fmaxf(v, -500.f), 500.f);
}

__device__ __forceinline__ unsigned short f2bf(float f) {
  unsigned int u = __float_as_uint(f);
  u += 0x7FFFu + ((u >> 16) & 1u);  // RNE; inputs always finite here
  return (unsigned short)(u >> 16);
}

__device__ __forceinline__ float bf2f(unsigned short u) {
  return __uint_as_float((unsigned)u << 16);
}

__device__ __forceinline__ unsigned pk2(float lo, float hi) {
  return (unsigned)f2bf(lo) | ((unsigned)f2bf(hi) << 16);
}

__device__ __forceinline__ uint4 pack4(float4 a, float4 b) {
  uint4 r;
  r.x = pk2(a.x, a.y); r.y = pk2(a.z, a.w);
  r.z = pk2(b.x, b.y); r.w = pk2(b.z, b.w);
  return r;
}

// async global->LDS, 16B per lane. LDS dest must be wave-uniform base + lane*16.
__device__ __forceinline__ void stage16(const unsigned short* g, unsigned short* l) {
  __builtin_amdgcn_global_load_lds(
      (const __attribute__((address_space(1))) void*)g,
      (__attribute__((address_space(3))) void*)l, 16, 0, 0);
}

__device__ __forceinline__ f32x4 mfma16(bf16x8 a, bf16x8 b, f32x4 c) {
  return __builtin_amdgcn_mfma_f32_16x16x32_bf16(a, b, c, 0, 0, 0);
}

// ---------------- router: LN -> logits -> softmax -> top2 + aux terms ----------------
__global__ __launch_bounds__(256) void router_kernel(
    const float* __restrict__ x, const float* __restrict__ lnw,
    const float* __restrict__ lnb, const float* __restrict__ rw,
    unsigned short* __restrict__ hf, int* __restrict__ top_i,
    float* __restrict__ top_w, float* __restrict__ probs_tok,
    float* __restrict__ zent) {
  int wv = threadIdx.x >> 6, lane = threadIdx.x & 63;
  int t = blockIdx.x * 4 + wv;  // one wave per token
  const float4* xr = (const float4*)(x + (size_t)t * HDIM);
  float4 v[4];
  float s = 0.f;
#pragma unroll
  for (int j = 0; j < 4; ++j) {
    float4 f = xr[j * 64 + lane];
    f.x = clamp500(f.x); f.y = clamp500(f.y);
    f.z = clamp500(f.z); f.w = clamp500(f.w);
    v[j] = f;
    ushort4 hh;
    hh.x = f2bf(f.x); hh.y = f2bf(f.y); hh.z = f2bf(f.z); hh.w = f2bf(f.w);
    ((ushort4*)hf)[(size_t)t * 256 + j * 64 + lane] = hh;
    s += f.x + f.y + f.z + f.w;
  }
#pragma unroll
  for (int m = 32; m; m >>= 1) s += __shfl_xor(s, m);
  float mu = s * (1.f / HDIM);
  float s2 = 0.f;
#pragma unroll
  for (int j = 0; j < 4; ++j) {
    float4 d = v[j];
    d.x -= mu; d.y -= mu; d.z -= mu; d.w -= mu;
    s2 += d.x * d.x + d.y * d.y + d.z * d.z + d.w * d.w;
  }
#pragma unroll
  for (int m = 32; m; m >>= 1) s2 += __shfl_xor(s2, m);
  float rstd = rsqrtf(s2 * (1.f / HDIM) + 1e-5f);
  float acc[8];
#pragma unroll
  for (int e = 0; e < 8; ++e) acc[e] = 0.f;
#pragma unroll
  for (int j = 0; j < 4; ++j) {
    float4 w = ((const float4*)lnw)[j * 64 + lane];
    float4 b = ((const float4*)lnb)[j * 64 + lane];
    float4 hn;
    hn.x = fminf(fmaxf((v[j].x - mu) * rstd * w.x + b.x, -50.f), 50.f);
    hn.y = fminf(fmaxf((v[j].y - mu) * rstd * w.y + b.y, -50.f), 50.f);
    hn.z = fminf(fmaxf((v[j].z - mu) * rstd * w.z + b.z, -50.f), 50.f);
    hn.w = fminf(fmaxf((v[j].w - mu) * rstd * w.w + b.w, -50.f), 50.f);
#pragma unroll
    for (int e = 0; e < 8; ++e) {
      float4 r = ((const float4*)(rw + e * HDIM))[j * 64 + lane];
      acc[e] += hn.x * r.x + hn.y * r.y + hn.z * r.z + hn.w * r.w;
    }
  }
#pragma unroll
  for (int e = 0; e < 8; ++e) {
    float a = acc[e];
#pragma unroll
    for (int m = 32; m; m >>= 1) a += __shfl_xor(a, m);
    acc[e] = a;
  }
  if (lane == 0) {
    float lg[8], mx = -1e30f;
#pragma unroll
    for (int e = 0; e < 8; ++e) {
      float l = fminf(fmaxf(acc[e], -10.f), 10.f);
      lg[e] = l;
      mx = fmaxf(mx, l);
    }
    float se = 0.f;
    float ex[8];
#pragma unroll
    for (int e = 0; e < 8; ++e) { ex[e] = expf(lg[e] - mx); se += ex[e]; }
    float inv = 1.f / se;
    float pr[8];
#pragma unroll
    for (int e = 0; e < 8; ++e) {
      float p = ex[e] * inv;
      pr[e] = fminf(fmaxf(p, 1e-4f), 1.f);
      probs_tok[t * 8 + e] = pr[e];
    }
    int i0 = 0; float v0 = pr[0];
#pragma unroll
    for (int e = 1; e < 8; ++e) if (pr[e] > v0) { v0 = pr[e]; i0 = e; }
    int i1 = -1; float v1 = -1.f;
#pragma unroll
    for (int e = 0; e < 8; ++e) if (e != i0 && pr[e] > v1) { v1 = pr[e]; i1 = e; }
    float dsum = fmaxf(v0 + v1, 1e-4f);
    top_i[2 * t] = i0; top_i[2 * t + 1] = i1;
    top_w[2 * t] = v0 / dsum; top_w[2 * t + 1] = v1 / dsum;
    float lse = mx + logf(se);
    zent[2 * t] = lse * lse;
    float ent = 0.f;
#pragma unroll
    for (int e = 0; e < 8; ++e) {
      float ps = fminf(fmaxf(pr[e], 1e-4f), 1.f - 1e-4f);
      ent -= ps * logf(ps);
    }
    zent[2 * t + 1] = ent;
  }
}

// ---------------- aux loss + 256-padded tile map (single block, deterministic) ----------------
__global__ __launch_bounds__(256) void aux_kernel(
    const int* __restrict__ top_i, const float* __restrict__ probs_tok,
    const float* __restrict__ zent, int* __restrict__ meta,
    int* __restrict__ ltok, float* __restrict__ lw,
    float* __restrict__ aux_out) {
  __shared__ int sc[8];
  __shared__ float red[256];
  __shared__ float sums[10];
  int tid = threadIdx.x;
  if (tid < 8) sc[tid] = 0;
  __syncthreads();
  for (int s = tid; s < 8192; s += 256) atomicAdd(&sc[top_i[s]], 1);
  // default-init padded token lists (scatter overwrites the live ones)
  for (int i = tid; i < ROWS_PAD; i += 256) { ltok[i] = 0; lw[i] = 0.f; }
  float pe[8] = {0, 0, 0, 0, 0, 0, 0, 0};
  float zs = 0.f, es = 0.f;
  for (int t = tid; t < 4096; t += 256) {
#pragma unroll
    for (int e = 0; e < 8; ++e) pe[e] += probs_tok[t * 8 + e];
    zs += zent[2 * t];
    es += zent[2 * t + 1];
  }
  for (int e = 0; e < 10; ++e) {
    float val = (e < 8) ? pe[e] : ((e == 8) ? zs : es);
    red[tid] = val;
    __syncthreads();
    for (int off = 128; off; off >>= 1) {
      if (tid < off) red[tid] += red[tid + off];
      __syncthreads();
    }
    if (tid == 0) sums[e] = red[0];
    __syncthreads();
  }
  if (tid == 0) {
    float lb = 0.f, usage = 0.f;
    for (int e = 0; e < 8; ++e) {
      float tpe = (float)sc[e] / 8192.f;
      float avg = sums[e] / 4096.f;
      lb += tpe * avg;
      usage += (tpe > 0.01f) ? 1.f : 0.f;
    }
    lb *= 8.f;
    float z_loss = (sums[8] / 4096.f) * 0.001f;
    float ent_loss = fmaxf(logf(8.f) - sums[9] / 4096.f, 0.f) * 0.01f;
    float util = (1.f - usage / 8.f) * 0.1f;
    float aux = fminf(fmaxf(lb + z_loss + ent_loss + util, 0.f), 10.f);
    *aux_out = aux;
    // 256-padded tile map
    int base = 0, tct = 0;
    for (int e = 0; e < 8; ++e) {
      int cnt = sc[e];
      meta[e] = cnt;
      meta[16 + e] = base;
      meta[32 + e] = 0;
      int nt = (cnt + 255) >> 8;
      for (int i = 0; i < nt; ++i) { meta[64 + tct] = e; meta[128 + tct] = base + i * 256; ++tct; }
      base += nt * 256;
    }
    meta[8] = TTOK;           // shared "expert"
    meta[16 + 8] = base;      // shared padded base
    meta[32 + 8] = 0;
    for (int i = 0; i < 16; ++i) { meta[64 + tct] = 8; meta[128 + tct] = base + i * 256; ++tct; }
    meta[48] = tct;
  }
}

// ---------------- scatter tokens into per-expert padded lists ----------------
__global__ __launch_bounds__(256) void scatter_kernel(
    const int* __restrict__ top_i, const float* __restrict__ top_w,
    int* __restrict__ meta, int* __restrict__ ltok, float* __restrict__ lw,
    int* __restrict__ rowslot) {
  int s = blockIdx.x * 256 + threadIdx.x;
  if (s < 8192) {
    int e = top_i[s];
    int pos = atomicAdd(&meta[32 + e], 1);
    int idx = meta[16 + e] + pos;
    ltok[idx] = s >> 1;
    lw[idx] = top_w[s];
    rowslot[s] = idx;
  }
  if (s < TTOK) {  // identity list for shared expert
    int sb = meta[16 + 8];
    ltok[sb + s] = s;
    lw[sb + s] = 1.f;
  }
}

// ---------------- GEMM1: P = clamp(silu(clamp(A*Wg^T)) * clamp(A*Wu^T)) ----------------
// BM=256, BN=128 (G and U), BK=64, 8 waves (2x4). A (bf16) via global_load_lds;
// weights fp32, reg-staged with COMMIT-AT-TOP: W regs loaded at iter t-1's top
// are committed at iter t's top (a full iteration old), then the SAME registers
// reload W[t+2]. Counted waits: VM_WAIT(4) at top (retires the 8 older W-loads,
// keeps 4 A-stages in flight), VM_WAIT(8) at bottom (retires the A-stages,
// keeps the 8 W-loads in flight across the barrier). One barrier/iter.
__global__ __launch_bounds__(512, 1) void gemm1_kernel(
    const unsigned short* __restrict__ hf,
    const float* __restrict__ wg_all, const float* __restrict__ wu_all,
    const float* __restrict__ swg, const float* __restrict__ swu,
    unsigned short* __restrict__ P,
    const int* __restrict__ meta, const int* __restrict__ ltok) {
  int mt = blockIdx.y, nt = blockIdx.x;
  if (mt >= meta[48]) return;
  int ex = meta[64 + mt];
  int r0 = meta[128 + mt];
  extern __shared__ unsigned short lds[];
  unsigned short* sA = lds;          // 2 x 16384 elems (256x64)
  unsigned short* sG = lds + 32768;  // 2 x 8192  (128x64)
  unsigned short* sU = lds + 49152;  // 2 x 8192
  int tid = threadIdx.x, lane = tid & 63, wv = tid >> 6;
  int wr = wv >> 2, wc = wv & 3;
  int l15 = lane & 15, l4 = lane >> 4;
  int srow = tid >> 3;              // A staging row within a 64-row issue
  int gch = (tid & 7) ^ (srow & 7); // inverse-swizzled A source 16B chunk
  int ldst = tid * 8;               // linear LDS dest elems within an issue
  const float* wg = (ex == 8) ? swg : wg_all + (size_t)ex * EXP_W_ELEMS;
  const float* wu = (ex == 8) ? swu : wu_all + (size_t)ex * EXP_W_ELEMS;
  int n0 = nt * 128;
  const unsigned short* srcA[4];
#pragma unroll
  for (int i = 0; i < 4; ++i) {
    int tok = ltok[r0 + i * 64 + srow];
    srcA[i] = hf + (size_t)tok * HDIM + gch * 8;
  }
  // weight reg-staging geometry: [128 rows][64 k-floats]; 512 thr -> 16 floats each
  int wrow = tid >> 2;            // 0..127
  int wc0 = (tid & 3) * 2;        // first of 2 owned 8-elem chunks
  const float* gsrc = wg + (size_t)(n0 + wrow) * HDIM + wc0 * 8;
  const float* usrc = wu + (size_t)(n0 + wrow) * HDIM + wc0 * 8;
  int wdst0 = wrow * 64 + ((wc0) ^ (wrow & 7)) * 8;
  int wdst1 = wrow * 64 + ((wc0 + 1) ^ (wrow & 7)) * 8;
  // swizzled ds_read chunk per kk (row&7 == lane&7 for all frag rows)
  int ch0 = (0 + l4) ^ (lane & 7);
  int ch1 = (4 + l4) ^ (lane & 7);
  int baseA = (wr * 128 + l15) * 64;
  int baseG = (wc * 32 + l15) * 64;

  f32x4 zero = {0.f, 0.f, 0.f, 0.f};
  f32x4 accg[8][2], accu[8][2];
#pragma unroll
  for (int m = 0; m < 8; ++m)
#pragma unroll
    for (int n = 0; n < 2; ++n) { accg[m][n] = zero; accu[m][n] = zero; }

  float4 g0, g1, g2, g3, u0, u1, u2, u3;
  // prologue: stage A[0]; load W[0]; drain; commit W[0]->buf0; load W[1]
#pragma unroll
  for (int i = 0; i < 4; ++i) stage16(srcA[i], &sA[i * 4096 + ldst]);
  g0 = *(const float4*)(gsrc);      g1 = *(const float4*)(gsrc + 4);
  g2 = *(const float4*)(gsrc + 8);  g3 = *(const float4*)(gsrc + 12);
  u0 = *(const float4*)(usrc);      u1 = *(const float4*)(usrc + 4);
  u2 = *(const float4*)(usrc + 8);  u3 = *(const float4*)(usrc + 12);
  VM_WAIT(0);
  *(uint4*)&sG[wdst0] = pack4(g0, g1);
  *(uint4*)&sG[wdst1] = pack4(g2, g3);
  *(uint4*)&sU[wdst0] = pack4(u0, u1);
  *(uint4*)&sU[wdst1] = pack4(u2, u3);
  g0 = *(const float4*)(gsrc + 64);      g1 = *(const float4*)(gsrc + 64 + 4);
  g2 = *(const float4*)(gsrc + 64 + 8);  g3 = *(const float4*)(gsrc + 64 + 12);
  u0 = *(const float4*)(usrc + 64);      u1 = *(const float4*)(usrc + 64 + 4);
  u2 = *(const float4*)(usrc + 64 + 8);  u3 = *(const float4*)(usrc + 64 + 12);
  LGKM0;
  SBAR;

  for (int t = 0; t < 16; ++t) {
    int cur = t & 1, nxt = cur ^ 1;
    int cbA = cur * 16384, cbG = cur * 8192;
    int nbA = nxt * 16384, nbG = nxt * 8192;
    int k1 = (t + 1) * 64, k2 = (t + 2) * 64;
    // ---- top: stage A[t+1]; commit W[t+1] (regs 1 iter old); reload W[t+2] ----
    if (t < 15) {
      stage16(srcA[0] + k1, &sA[nbA + 0 * 4096 + ldst]);
      stage16(srcA[1] + k1, &sA[nbA + 1 * 4096 + ldst]);
      stage16(srcA[2] + k1, &sA[nbA + 2 * 4096 + ldst]);
      stage16(srcA[3] + k1, &sA[nbA + 3 * 4096 + ldst]);
      VM_WAIT(4);   // retires the 8 older W[t+1] loads; A-stages stay in flight
      *(uint4*)&sG[nbG + wdst0] = pack4(g0, g1);
      *(uint4*)&sG[nbG + wdst1] = pack4(g2, g3);
      *(uint4*)&sU[nbG + wdst0] = pack4(u0, u1);
      *(uint4*)&sU[nbG + wdst1] = pack4(u2, u3);
    }
    if (t < 14) {
      g0 = *(const float4*)(gsrc + k2);      g1 = *(const float4*)(gsrc + k2 + 4);
      g2 = *(const float4*)(gsrc + k2 + 8);  g3 = *(const float4*)(gsrc + k2 + 12);
      u0 = *(const float4*)(usrc + k2);      u1 = *(const float4*)(usrc + k2 + 4);
      u2 = *(const float4*)(usrc + k2 + 8);  u3 = *(const float4*)(usrc + k2 + 12);
    }
    FENCE;
    bf16x8 af0[8], af1[8], gf0[2], gf1[2], uf0[2], uf1[2];
    // ---- kk0 ----
#pragma unroll
    for (int m = 0; m < 8; ++m)
      af0[m] = *(const bf16x8*)&sA[cbA + baseA + m * 1024 + ch0 * 8];
#pragma unroll
    for (int n = 0; n < 2; ++n)
      gf0[n] = *(const bf16x8*)&sG[cbG + baseG + n * 1024 + ch0 * 8];
    PRIO_HI;
#pragma unroll
    for (int m = 0; m < 8; ++m)
#pragma unroll
      for (int n = 0; n < 2; ++n)
        accg[m][n] = mfma16(af0[m], gf0[n], accg[m][n]);
    PRIO_LO;
#pragma unroll
    for (int n = 0; n < 2; ++n)
      uf0[n] = *(const bf16x8*)&sU[cbG + baseG + n * 1024 + ch0 * 8];
    PRIO_HI;
#pragma unroll
    for (int m = 0; m < 8; ++m)
#pragma unroll
      for (int n = 0; n < 2; ++n)
        accu[m][n] = mfma16(af0[m], uf0[n], accu[m][n]);
    PRIO_LO;
    // ---- kk1 ----
#pragma unroll
    for (int m = 0; m < 8; ++m)
      af1[m] = *(const bf16x8*)&sA[cbA + baseA + m * 1024 + ch1 * 8];
#pragma unroll
    for (int n = 0; n < 2; ++n)
      gf1[n] = *(const bf16x8*)&sG[cbG + baseG + n * 1024 + ch1 * 8];
    PRIO_HI;
#pragma unroll
    for (int m = 0; m < 8; ++m)
#pragma unroll
      for (int n = 0; n < 2; ++n)
        accg[m][n] = mfma16(af1[m], gf1[n], accg[m][n]);
    PRIO_LO;
#pragma unroll
    for (int n = 0; n < 2; ++n)
      uf1[n] = *(const bf16x8*)&sU[cbG + baseG + n * 1024 + ch1 * 8];
    PRIO_HI;
#pragma unroll
    for (int m = 0; m < 8; ++m)
#pragma unroll
      for (int n = 0; n < 2; ++n)
        accu[m][n] = mfma16(af1[m], uf1[n], accu[m][n]);
    PRIO_LO;
    FENCE;
    // ---- bottom: retire only the A-stages; W-loads stay in flight ----
    if (t < 14) { VM_WAIT(8); } else { VM_WAIT(0); }
    LGKM0;
    SBAR;
  }
  // epilogue: SwiGLU, write bf16 P (padded rows junk, never read)
  int rbase = r0 + wr * 128 + l4 * 4;
  int cbase = n0 + wc * 32 + l15;
#pragma unroll
  for (int m = 0; m < 8; ++m) {
#pragma unroll
    for (int r = 0; r < 4; ++r) {
      size_t prow = (size_t)(rbase + m * 16 + r) * IDIM;
#pragma unroll
      for (int n = 0; n < 2; ++n) {
        float g = clamp500(accg[m][n][r]);
        float u = clamp500(accu[m][n][r]);
        float sl = g / (1.f + __expf(-g));
        float p = clamp500(sl * u);
        P[prow + cbase + n * 16] = f2bf(p);
      }
    }
  }
}

// ---------------- GEMM2: slot = weight * clamp(P*Wd^T)  (shared: clamp(clamp(.)*sig)) ----------------
// BM=256, BN=256, BK=64, 8 waves. Same commit-at-top reg-staged weight pipeline.
__global__ __launch_bounds__(512, 1) void gemm2_kernel(
    const unsigned short* __restrict__ P,
    const float* __restrict__ wd_all, const float* __restrict__ swd,
    unsigned short* __restrict__ slot,
    const int* __restrict__ meta, const float* __restrict__ lw,
    const float* __restrict__ sgate) {
  int mt = blockIdx.y, nt = blockIdx.x;
  if (mt >= meta[48]) return;
  int ex = meta[64 + mt];
  int r0 = meta[128 + mt];
  extern __shared__ unsigned short lds[];
  unsigned short* sA = lds;          // 2 x 16384 (256x64)
  unsigned short* sB = lds + 32768;  // 2 x 16384 (256x64)
  int tid = threadIdx.x, lane = tid & 63, wv = tid >> 6;
  int wr = wv >> 2, wc = wv & 3;
  int l15 = lane & 15, l4 = lane >> 4;
  int srow = tid >> 3;
  int gch = (tid & 7) ^ (srow & 7);
  int ldst = tid * 8;
  const float* wd = (ex == 8) ? swd : wd_all + (size_t)ex * EXP_W_ELEMS;
  int n0 = nt * 256;
  const unsigned short* srcA[4];
#pragma unroll
  for (int i = 0; i < 4; ++i)
    srcA[i] = P + (size_t)(r0 + i * 64 + srow) * IDIM + gch * 8;
  // weight staging: [256 rows][64 k-floats]; 512 thr -> 32 floats each
  int wrow = tid >> 1;            // 0..255
  int wc0 = (tid & 1) * 4;        // first of 4 owned chunks
  const float* bsrc = wd + (size_t)(n0 + wrow) * IDIM + wc0 * 8;
  int wdst0 = wrow * 64 + ((wc0) ^ (wrow & 7)) * 8;
  int wdst1 = wrow * 64 + ((wc0 + 1) ^ (wrow & 7)) * 8;
  int wdst2 = wrow * 64 + ((wc0 + 2) ^ (wrow & 7)) * 8;
  int wdst3 = wrow * 64 + ((wc0 + 3) ^ (wrow & 7)) * 8;
  int ch0 = (0 + l4) ^ (lane & 7);
  int ch1 = (4 + l4) ^ (lane & 7);
  int baseA = (wr * 128 + l15) * 64;
  int baseB = (wc * 64 + l15) * 64;

  f32x4 zero = {0.f, 0.f, 0.f, 0.f};
  f32x4 acc[8][4];
#pragma unroll
  for (int m = 0; m < 8; ++m)
#pragma unroll
    for (int n = 0; n < 4; ++n) acc[m][n] = zero;

  float4 b0, b1, b2, b3, b4, b5, b6, b7;
  // prologue
#pragma unroll
  for (int i = 0; i < 4; ++i) stage16(srcA[i], &sA[i * 4096 + ldst]);
  b0 = *(const float4*)(bsrc);       b1 = *(const float4*)(bsrc + 4);
  b2 = *(const float4*)(bsrc + 8);   b3 = *(const float4*)(bsrc + 12);
  b4 = *(const float4*)(bsrc + 16);  b5 = *(const float4*)(bsrc + 20);
  b6 = *(const float4*)(bsrc + 24);  b7 = *(const float4*)(bsrc + 28);
  VM_WAIT(0);
  *(uint4*)&sB[wdst0] = pack4(b0, b1);
  *(uint4*)&sB[wdst1] = pack4(b2, b3);
  *(uint4*)&sB[wdst2] = pack4(b4, b5);
  *(uint4*)&sB[wdst3] = pack4(b6, b7);
  b0 = *(const float4*)(bsrc + 64);       b1 = *(const float4*)(bsrc + 64 + 4);
  b2 = *(const float4*)(bsrc + 64 + 8);   b3 = *(const float4*)(bsrc + 64 + 12);
  b4 = *(const float4*)(bsrc + 64 + 16);  b5 = *(const float4*)(bsrc + 64 + 20);
  b6 = *(const float4*)(bsrc + 64 + 24);  b7 = *(const float4*)(bsrc + 64 + 28);
  LGKM0;
  SBAR;

  for (int t = 0; t < 32; ++t) {
    int cur = t & 1, nxt = cur ^ 1;
    int cb = cur * 16384, nb = nxt * 16384;
    int k1 = (t + 1) * 64, k2 = (t + 2) * 64;
    // ---- top ----
    if (t < 31) {
      stage16(srcA[0] + k1, &sA[nb + 0 * 4096 + ldst]);
      stage16(srcA[1] + k1, &sA[nb + 1 * 4096 + ldst]);
      stage16(srcA[2] + k1, &sA[nb + 2 * 4096 + ldst]);
      stage16(srcA[3] + k1, &sA[nb + 3 * 4096 + ldst]);
      VM_WAIT(4);   // retires the 8 older W[t+1] loads
      *(uint4*)&sB[nb + wdst0] = pack4(b0, b1);
      *(uint4*)&sB[nb + wdst1] = pack4(b2, b3);
      *(uint4*)&sB[nb + wdst2] = pack4(b4, b5);
      *(uint4*)&sB[nb + wdst3] = pack4(b6, b7);
    }
    if (t < 30) {
      b0 = *(const float4*)(bsrc + k2);       b1 = *(const float4*)(bsrc + k2 + 4);
      b2 = *(const float4*)(bsrc + k2 + 8);   b3 = *(const float4*)(bsrc + k2 + 12);
      b4 = *(const float4*)(bsrc + k2 + 16);  b5 = *(const float4*)(bsrc + k2 + 20);
      b6 = *(const float4*)(bsrc + k2 + 24);  b7 = *(const float4*)(bsrc + k2 + 28);
    }
    FENCE;
    bf16x8 af0[8], af1[8], bf0[4], bf1[4];
    // ---- kk0 ----
#pragma unroll
    for (int m = 0; m < 8; ++m)
      af0[m] = *(const bf16x8*)&sA[cb + baseA + m * 1024 + ch0 * 8];
#pragma unroll
    for (int n = 0; n < 4; ++n)
      bf0[n] = *(const bf16x8*)&sB[cb + baseB + n * 1024 + ch0 * 8];
    PRIO_HI;
#pragma unroll
    for (int m = 0; m < 8; ++m)
#pragma unroll
      for (int n = 0; n < 4; ++n)
        acc[m][n] = mfma16(af0[m], bf0[n], acc[m][n]);
    PRIO_LO;
    // ---- kk1 ----
#pragma unroll
    for (int m = 0; m < 8; ++m)
      af1[m] = *(const bf16x8*)&sA[cb + baseA + m * 1024 + ch1 * 8];
#pragma unroll
    for (int n = 0; n < 4; ++n)
      bf1[n] = *(const bf16x8*)&sB[cb + baseB + n * 1024 + ch1 * 8];
    PRIO_HI;
#pragma unroll
    for (int m = 0; m < 8; ++m)
#pragma unroll
      for (int n = 0; n < 4; ++n)
        acc[m][n] = mfma16(af1[m], bf1[n], acc[m][n]);
    PRIO_LO;
    FENCE;
    // ---- bottom ----
    if (t < 30) { VM_WAIT(8); } else { VM_WAIT(0); }
    LGKM0;
    SBAR;
  }
  float gsig = 1.f / (1.f + __expf(-sgate[0]));
  int rbase = r0 + wr * 128 + l4 * 4;
  int cbase = n0 + wc * 64 + l15;
#pragma unroll
  for (int m = 0; m < 8; ++m) {
#pragma unroll
    for (int r = 0; r < 4; ++r) {
      int row = rbase + m * 16 + r;
      float wgt = (ex == 8) ? 1.f : lw[row];
      size_t srow_o = (size_t)row * HDIM;
#pragma unroll
      for (int n = 0; n < 4; ++n) {
        float o = clamp500(acc[m][n][r]);
        float val = (ex == 8) ? clamp500(o * gsig) : wgt * o;
        slot[srow_o + cbase + n * 16] = f2bf(val);
      }
    }
  }
}

// ---------------- combine: final = clamp(slot0 + slot1 + shared) ----------------
__global__ __launch_bounds__(256) void combine_kernel(
    const unsigned short* __restrict__ slot, const int* __restrict__ rowslot,
    const int* __restrict__ meta, float* __restrict__ out) {
  int i = blockIdx.x * 256 + threadIdx.x;  // 4-elem group index
  int t = i >> 8;
  int c = (i & 255) * 4;
  int sb = meta[16 + 8];
  int r0 = rowslot[2 * t], r1 = rowslot[2 * t + 1];
  ushort4 va = *(const ushort4*)(slot + (size_t)r0 * HDIM + c);
  ushort4 vb = *(const ushort4*)(slot + (size_t)r1 * HDIM + c);
  ushort4 vs = *(const ushort4*)(slot + (size_t)(sb + t) * HDIM + c);
  float4 o;
  o.x = clamp500(bf2f(va.x) + bf2f(vb.x) + bf2f(vs.x));
  o.y = clamp500(bf2f(va.y) + bf2f(vb.y) + bf2f(vs.y));
  o.z = clamp500(bf2f(va.z) + bf2f(vb.z) + bf2f(vs.z));
  o.w = clamp500(bf2f(va.w) + bf2f(vb.w) + bf2f(vs.w));
  *(float4*)(out + (size_t)t * HDIM + c) = o;
}

// ---------------- launch ----------------
extern "C" void kernel_launch(void* const* d_in, const int* in_sizes, int n_in,
                              void* d_out, int out_size, void* d_ws, size_t ws_size,
                              hipStream_t stream) {
  const float* x     = (const float*)d_in[0];
  const float* lnw   = (const float*)d_in[1];
  const float* lnb   = (const float*)d_in[2];
  const float* rw    = (const float*)d_in[3];
  const float* wg_f  = (const float*)d_in[4];
  const float* wu_f  = (const float*)d_in[5];
  const float* wd_f  = (const float*)d_in[6];
  const float* swg_f = (const float*)d_in[7];
  const float* swu_f = (const float*)d_in[8];
  const float* swd_f = (const float*)d_in[9];
  const float* sgate = (const float*)d_in[10];
  float* out = (float*)d_out;

  char* ws = (char*)d_ws;
  unsigned short* hf  = (unsigned short*)(ws + OFF_HF);
  unsigned short* P   = (unsigned short*)(ws + OFF_P);
  unsigned short* slot = (unsigned short*)(ws + OFF_SLOT);
  int*   top_i   = (int*)(ws + OFF_TOPI);
  float* top_w   = (float*)(ws + OFF_TOPW);
  float* probs   = (float*)(ws + OFF_PROB);
  float* zent    = (float*)(ws + OFF_ZENT);
  int*   meta    = (int*)(ws + OFF_META);
  int*   ltok    = (int*)(ws + OFF_LTOK);
  float* lw      = (float*)(ws + OFF_LW);
  int*   rowslot = (int*)(ws + OFF_ROWS);

  hipFuncSetAttribute((const void*)gemm1_kernel,
                      hipFuncAttributeMaxDynamicSharedMemorySize, 131072);
  hipFuncSetAttribute((const void*)gemm2_kernel,
                      hipFuncAttributeMaxDynamicSharedMemorySize, 131072);

  router_kernel<<<TTOK / 4, 256, 0, stream>>>(x, lnw, lnb, rw, hf, top_i, top_w, probs, zent);
  aux_kernel<<<1, 256, 0, stream>>>(top_i, probs, zent, meta, ltok, lw, out + (size_t)TTOK * HDIM);
  scatter_kernel<<<32, 256, 0, stream>>>(top_i, top_w, meta, ltok, lw, rowslot);

  gemm1_kernel<<<dim3(16, MT_MAX), 512, 131072, stream>>>(
      hf, wg_f, wu_f, swg_f, swu_f, P, meta, ltok);
  gemm2_kernel<<<dim3(4, MT_MAX), 512, 131072, stream>>>(
      P, wd_f, swd_f, slot, meta, lw, sgate);
  combine_kernel<<<TTOK * HDIM / 4 / 256, 256, 0, stream>>>(slot, rowslot, meta, out);
}

// Round 8
// 355.789 us; speedup vs baseline: 1.2072x; 1.0997x over previous
//
#include <hip/hip_runtime.h>
#include <hip/hip_bf16.h>
#include <cstdint>
#include <cstddef>

// ---------------- types ----------------
typedef __attribute__((ext_vector_type(8))) short bf16x8;
typedef __attribute__((ext_vector_type(4))) float f32x4;

#define HDIM 1024
#define IDIM 2048
#define TTOK 4096
#define NEXP 8
#define ROWS_PAD 14336          // 256-padded routed (<=10240) + shared 4096
#define MT_MAX 64               // max 256-row m-tiles: <=40 routed + 16 shared
#define EXP_W_ELEMS 2097152ull  // 2048*1024 elems per weight matrix per expert

// ---------------- workspace layout (bytes) ----------------
#define OFF_WG   0ull
#define OFF_WU   (OFF_WG + 9ull * EXP_W_ELEMS * 2ull)
#define OFF_WD   (OFF_WU + 9ull * EXP_W_ELEMS * 2ull)
#define OFF_HF   (OFF_WD + 9ull * EXP_W_ELEMS * 2ull)            // [4096][1024] bf16
#define OFF_P    (OFF_HF + 4096ull * 1024ull * 2ull)             // [ROWS_PAD][2048] bf16
#define OFF_SLOT (OFF_P  + (size_t)ROWS_PAD * 2048ull * 2ull)    // [ROWS_PAD][1024] bf16
#define OFF_TOPI (OFF_SLOT + (size_t)ROWS_PAD * 1024ull * 2ull)  // [8192] int
#define OFF_TOPW (OFF_TOPI + 8192ull * 4ull)                     // [8192] f32
#define OFF_PROB (OFF_TOPW + 8192ull * 4ull)                     // [4096][8] f32
#define OFF_ZENT (OFF_PROB + 4096ull * 8ull * 4ull)              // [4096][2] f32
#define OFF_META (OFF_ZENT + 4096ull * 2ull * 4ull)              // ints, see below
#define OFF_LTOK (OFF_META + 4096ull)                            // [ROWS_PAD] int
#define OFF_LW   (OFF_LTOK + (size_t)ROWS_PAD * 4ull)            // [ROWS_PAD] f32
#define OFF_ROWS (OFF_LW + (size_t)ROWS_PAD * 4ull)              // [8192] int

// meta (ints): [0..8]=cnt, [16..24]=256-padded base, [32..40]=cursor,
//              [48]=ntiles256, [64..127]=tile->expert, [128..191]=tile->row0

#define VM_WAIT(n) asm volatile("s_waitcnt vmcnt(" #n ")" ::: "memory")
#define SBAR __builtin_amdgcn_s_barrier()
#define FENCE __builtin_amdgcn_sched_barrier(0)
#define PRIO_HI __builtin_amdgcn_s_setprio(1)
#define PRIO_LO __builtin_amdgcn_s_setprio(0)

__device__ __forceinline__ float clamp500(float v) {
  return fminf(fmaxf(v, -500.f), 500.f);
}

__device__ __forceinline__ unsigned short f2bf(float f) {
  unsigned int u = __float_as_uint(f);
  u += 0x7FFFu + ((u >> 16) & 1u);  // RNE; inputs always finite here
  return (unsigned short)(u >> 16);
}

__device__ __forceinline__ float bf2f(unsigned short u) {
  return __uint_as_float((unsigned)u << 16);
}

// async global->LDS, 16B per lane. LDS dest must be wave-uniform base + lane*16.
__device__ __forceinline__ void stage16(const unsigned short* g, unsigned short* l) {
  __builtin_amdgcn_global_load_lds(
      (const __attribute__((address_space(1))) void*)g,
      (__attribute__((address_space(3))) void*)l, 16, 0, 0);
}

__device__ __forceinline__ f32x4 mfma16(bf16x8 a, bf16x8 b, f32x4 c) {
  return __builtin_amdgcn_mfma_f32_16x16x32_bf16(a, b, c, 0, 0, 0);
}

// ---------------- merged router + weight-conversion kernel ----------------
// blocks [0,1024): one wave per token -> LN, logits, softmax, top2, aux terms.
// blocks [1024,3072): grid-stride fp32->bf16 convert of all 6 weight tensors.
// Router is latency-bound, cvt is BW-bound -> concurrent execution across CUs
// costs ~max() instead of sum().
#define CVT_BLKS 2048
#define E4 (8ull * EXP_W_ELEMS / 4ull)   // float4s per big matrix (8 experts)
#define S4 (EXP_W_ELEMS / 4ull)          // float4s per shared matrix
__global__ __launch_bounds__(256) void router_cvt_kernel(
    const float* __restrict__ x, const float* __restrict__ lnw,
    const float* __restrict__ lnb, const float* __restrict__ rw,
    const float* __restrict__ wg_f, const float* __restrict__ wu_f,
    const float* __restrict__ wd_f, const float* __restrict__ swg_f,
    const float* __restrict__ swu_f, const float* __restrict__ swd_f,
    unsigned short* __restrict__ wgb, unsigned short* __restrict__ wub,
    unsigned short* __restrict__ wdb,
    unsigned short* __restrict__ hf, int* __restrict__ top_i,
    float* __restrict__ top_w, float* __restrict__ probs_tok,
    float* __restrict__ zent) {
  if (blockIdx.x >= 1024) {
    // ---- cvt role ----
    size_t i = (size_t)(blockIdx.x - 1024) * 256 + threadIdx.x;
    const size_t stride = (size_t)CVT_BLKS * 256;
    const size_t n4 = 3 * (E4 + S4);
    for (; i < n4; i += stride) {
      size_t j = i;
      const float* src;
      unsigned short* dst;
      if (j < E4) { src = wg_f; dst = wgb; }
      else { j -= E4;
        if (j < S4) { src = swg_f; dst = wgb + 8 * EXP_W_ELEMS; }
        else { j -= S4;
          if (j < E4) { src = wu_f; dst = wub; }
          else { j -= E4;
            if (j < S4) { src = swu_f; dst = wub + 8 * EXP_W_ELEMS; }
            else { j -= S4;
              if (j < E4) { src = wd_f; dst = wdb; }
              else { j -= E4; src = swd_f; dst = wdb + 8 * EXP_W_ELEMS; }
            }
          }
        }
      }
      float4 f = ((const float4*)src)[j];
      uint2 pk;
      pk.x = (unsigned)f2bf(f.x) | ((unsigned)f2bf(f.y) << 16);
      pk.y = (unsigned)f2bf(f.z) | ((unsigned)f2bf(f.w) << 16);
      ((uint2*)dst)[j] = pk;
    }
    return;
  }
  // ---- router role ----
  int wv = threadIdx.x >> 6, lane = threadIdx.x & 63;
  int t = blockIdx.x * 4 + wv;
  const float4* xr = (const float4*)(x + (size_t)t * HDIM);
  float4 v[4];
  float s = 0.f;
#pragma unroll
  for (int j = 0; j < 4; ++j) {
    float4 f = xr[j * 64 + lane];
    f.x = clamp500(f.x); f.y = clamp500(f.y);
    f.z = clamp500(f.z); f.w = clamp500(f.w);
    v[j] = f;
    ushort4 hh;
    hh.x = f2bf(f.x); hh.y = f2bf(f.y); hh.z = f2bf(f.z); hh.w = f2bf(f.w);
    ((ushort4*)hf)[(size_t)t * 256 + j * 64 + lane] = hh;
    s += f.x + f.y + f.z + f.w;
  }
#pragma unroll
  for (int m = 32; m; m >>= 1) s += __shfl_xor(s, m);
  float mu = s * (1.f / HDIM);
  float s2 = 0.f;
#pragma unroll
  for (int j = 0; j < 4; ++j) {
    float4 d = v[j];
    d.x -= mu; d.y -= mu; d.z -= mu; d.w -= mu;
    s2 += d.x * d.x + d.y * d.y + d.z * d.z + d.w * d.w;
  }
#pragma unroll
  for (int m = 32; m; m >>= 1) s2 += __shfl_xor(s2, m);
  float rstd = rsqrtf(s2 * (1.f / HDIM) + 1e-5f);
  float acc[8];
#pragma unroll
  for (int e = 0; e < 8; ++e) acc[e] = 0.f;
#pragma unroll
  for (int j = 0; j < 4; ++j) {
    float4 w = ((const float4*)lnw)[j * 64 + lane];
    float4 b = ((const float4*)lnb)[j * 64 + lane];
    float4 hn;
    hn.x = fminf(fmaxf((v[j].x - mu) * rstd * w.x + b.x, -50.f), 50.f);
    hn.y = fminf(fmaxf((v[j].y - mu) * rstd * w.y + b.y, -50.f), 50.f);
    hn.z = fminf(fmaxf((v[j].z - mu) * rstd * w.z + b.z, -50.f), 50.f);
    hn.w = fminf(fmaxf((v[j].w - mu) * rstd * w.w + b.w, -50.f), 50.f);
#pragma unroll
    for (int e = 0; e < 8; ++e) {
      float4 r = ((const float4*)(rw + e * HDIM))[j * 64 + lane];
      acc[e] += hn.x * r.x + hn.y * r.y + hn.z * r.z + hn.w * r.w;
    }
  }
#pragma unroll
  for (int e = 0; e < 8; ++e) {
    float a = acc[e];
#pragma unroll
    for (int m = 32; m; m >>= 1) a += __shfl_xor(a, m);
    acc[e] = a;
  }
  if (lane == 0) {
    float lg[8], mx = -1e30f;
#pragma unroll
    for (int e = 0; e < 8; ++e) {
      float l = fminf(fmaxf(acc[e], -10.f), 10.f);
      lg[e] = l;
      mx = fmaxf(mx, l);
    }
    float se = 0.f;
    float ex[8];
#pragma unroll
    for (int e = 0; e < 8; ++e) { ex[e] = expf(lg[e] - mx); se += ex[e]; }
    float inv = 1.f / se;
    float pr[8];
#pragma unroll
    for (int e = 0; e < 8; ++e) {
      float p = ex[e] * inv;
      pr[e] = fminf(fmaxf(p, 1e-4f), 1.f);
      probs_tok[t * 8 + e] = pr[e];
    }
    int i0 = 0; float v0 = pr[0];
#pragma unroll
    for (int e = 1; e < 8; ++e) if (pr[e] > v0) { v0 = pr[e]; i0 = e; }
    int i1 = -1; float v1 = -1.f;
#pragma unroll
    for (int e = 0; e < 8; ++e) if (e != i0 && pr[e] > v1) { v1 = pr[e]; i1 = e; }
    float dsum = fmaxf(v0 + v1, 1e-4f);
    top_i[2 * t] = i0; top_i[2 * t + 1] = i1;
    top_w[2 * t] = v0 / dsum; top_w[2 * t + 1] = v1 / dsum;
    float lse = mx + logf(se);
    zent[2 * t] = lse * lse;
    float ent = 0.f;
#pragma unroll
    for (int e = 0; e < 8; ++e) {
      float ps = fminf(fmaxf(pr[e], 1e-4f), 1.f - 1e-4f);
      ent -= ps * logf(ps);
    }
    zent[2 * t + 1] = ent;
  }
}

// ---------------- aux loss + 256-padded tile map (single block, deterministic) ----------------
__global__ __launch_bounds__(256) void aux_kernel(
    const int* __restrict__ top_i, const float* __restrict__ probs_tok,
    const float* __restrict__ zent, int* __restrict__ meta,
    int* __restrict__ ltok, float* __restrict__ lw,
    float* __restrict__ aux_out) {
  __shared__ int sc[8];
  __shared__ float red[256];
  __shared__ float sums[10];
  int tid = threadIdx.x;
  if (tid < 8) sc[tid] = 0;
  __syncthreads();
  for (int s = tid; s < 8192; s += 256) atomicAdd(&sc[top_i[s]], 1);
  // default-init padded token lists (scatter overwrites the live ones)
  for (int i = tid; i < ROWS_PAD; i += 256) { ltok[i] = 0; lw[i] = 0.f; }
  float pe[8] = {0, 0, 0, 0, 0, 0, 0, 0};
  float zs = 0.f, es = 0.f;
  for (int t = tid; t < 4096; t += 256) {
#pragma unroll
    for (int e = 0; e < 8; ++e) pe[e] += probs_tok[t * 8 + e];
    zs += zent[2 * t];
    es += zent[2 * t + 1];
  }
  for (int e = 0; e < 10; ++e) {
    float val = (e < 8) ? pe[e] : ((e == 8) ? zs : es);
    red[tid] = val;
    __syncthreads();
    for (int off = 128; off; off >>= 1) {
      if (tid < off) red[tid] += red[tid + off];
      __syncthreads();
    }
    if (tid == 0) sums[e] = red[0];
    __syncthreads();
  }
  if (tid == 0) {
    float lb = 0.f, usage = 0.f;
    for (int e = 0; e < 8; ++e) {
      float tpe = (float)sc[e] / 8192.f;
      float avg = sums[e] / 4096.f;
      lb += tpe * avg;
      usage += (tpe > 0.01f) ? 1.f : 0.f;
    }
    lb *= 8.f;
    float z_loss = (sums[8] / 4096.f) * 0.001f;
    float ent_loss = fmaxf(logf(8.f) - sums[9] / 4096.f, 0.f) * 0.01f;
    float util = (1.f - usage / 8.f) * 0.1f;
    float aux = fminf(fmaxf(lb + z_loss + ent_loss + util, 0.f), 10.f);
    *aux_out = aux;
    // 256-padded tile map
    int base = 0, tct = 0;
    for (int e = 0; e < 8; ++e) {
      int cnt = sc[e];
      meta[e] = cnt;
      meta[16 + e] = base;
      meta[32 + e] = 0;
      int nt = (cnt + 255) >> 8;
      for (int i = 0; i < nt; ++i) { meta[64 + tct] = e; meta[128 + tct] = base + i * 256; ++tct; }
      base += nt * 256;
    }
    meta[8] = TTOK;           // shared "expert"
    meta[16 + 8] = base;      // shared padded base
    meta[32 + 8] = 0;
    for (int i = 0; i < 16; ++i) { meta[64 + tct] = 8; meta[128 + tct] = base + i * 256; ++tct; }
    meta[48] = tct;
  }
}

// ---------------- scatter tokens into per-expert padded lists ----------------
__global__ __launch_bounds__(256) void scatter_kernel(
    const int* __restrict__ top_i, const float* __restrict__ top_w,
    int* __restrict__ meta, int* __restrict__ ltok, float* __restrict__ lw,
    int* __restrict__ rowslot) {
  int s = blockIdx.x * 256 + threadIdx.x;
  if (s < 8192) {
    int e = top_i[s];
    int pos = atomicAdd(&meta[32 + e], 1);
    int idx = meta[16 + e] + pos;
    ltok[idx] = s >> 1;
    lw[idx] = top_w[s];
    rowslot[s] = idx;
  }
  if (s < TTOK) {  // identity list for shared expert
    int sb = meta[16 + 8];
    ltok[sb + s] = s;
    lw[sb + s] = 1.f;
  }
}

// ---------------- GEMM1: P = clamp(silu(clamp(A*Wg^T)) * clamp(A*Wu^T)) ----------------
// BM=256, BN=128 (G and U), BK=64, 8 waves (2x4). All operands bf16 via
// global_load_lds. Pipelined: 8 stages for buf nxt at iter top, vmcnt(8)
// waits only the previous iter's loads, 2 barriers/iter. (Proven R4 structure.)
__global__ __launch_bounds__(512, 1) void gemm1_kernel(
    const unsigned short* __restrict__ hf,
    const unsigned short* __restrict__ wg_all,
    const unsigned short* __restrict__ wu_all,
    unsigned short* __restrict__ P,
    const int* __restrict__ meta, const int* __restrict__ ltok) {
  int mt = blockIdx.y, nt = blockIdx.x;
  if (mt >= meta[48]) return;
  int ex = meta[64 + mt];
  int r0 = meta[128 + mt];
  extern __shared__ unsigned short lds[];
  unsigned short* sA = lds;          // 2 x 16384 elems (256x64)
  unsigned short* sG = lds + 32768;  // 2 x 8192  (128x64)
  unsigned short* sU = lds + 49152;  // 2 x 8192
  int tid = threadIdx.x, lane = tid & 63, wv = tid >> 6;
  int wr = wv >> 2, wc = wv & 3;
  int l15 = lane & 15, l4 = lane >> 4;
  int srow = tid >> 3;              // staging row within a 64-row issue
  int gch = (tid & 7) ^ (srow & 7); // inverse-swizzled source 16B chunk
  int ldst = tid * 8;               // linear LDS dest elems within an issue
  const unsigned short* wg = wg_all + (size_t)ex * EXP_W_ELEMS;
  const unsigned short* wu = wu_all + (size_t)ex * EXP_W_ELEMS;
  int n0 = nt * 128;
  const unsigned short* srcA[4];
#pragma unroll
  for (int i = 0; i < 4; ++i) {
    int tok = ltok[r0 + i * 64 + srow];
    srcA[i] = hf + (size_t)tok * HDIM + gch * 8;
  }
  const unsigned short* srcG[2];
  const unsigned short* srcU[2];
#pragma unroll
  for (int i = 0; i < 2; ++i) {
    srcG[i] = wg + (size_t)(n0 + i * 64 + srow) * HDIM + gch * 8;
    srcU[i] = wu + (size_t)(n0 + i * 64 + srow) * HDIM + gch * 8;
  }
  // swizzled ds_read chunk per kk (row&7 == lane&7 for all frag rows)
  int ch0 = (0 + l4) ^ (lane & 7);
  int ch1 = (4 + l4) ^ (lane & 7);
  int baseA = (wr * 128 + l15) * 64;
  int baseG = (wc * 32 + l15) * 64;

  f32x4 zero = {0.f, 0.f, 0.f, 0.f};
  f32x4 accg[8][2], accu[8][2];
#pragma unroll
  for (int m = 0; m < 8; ++m)
#pragma unroll
    for (int n = 0; n < 2; ++n) { accg[m][n] = zero; accu[m][n] = zero; }

  // prologue: stage K-step 0 into buf0 (no wait here; t=0 top waits)
#pragma unroll
  for (int i = 0; i < 4; ++i) stage16(srcA[i], &sA[i * 4096 + ldst]);
#pragma unroll
  for (int i = 0; i < 2; ++i) stage16(srcG[i], &sG[i * 4096 + ldst]);
#pragma unroll
  for (int i = 0; i < 2; ++i) stage16(srcU[i], &sU[i * 4096 + ldst]);

  for (int t = 0; t < 16; ++t) {
    int cur = t & 1, nxt = cur ^ 1;
    int cbA = cur * 16384, cbG = cur * 8192;
    int nbA = nxt * 16384, nbG = nxt * 8192;
    if (t < 15) {
      int k1 = (t + 1) * 64;
      stage16(srcA[0] + k1, &sA[nbA + 0 * 4096 + ldst]);
      stage16(srcA[1] + k1, &sA[nbA + 1 * 4096 + ldst]);
      stage16(srcA[2] + k1, &sA[nbA + 2 * 4096 + ldst]);
      stage16(srcA[3] + k1, &sA[nbA + 3 * 4096 + ldst]);
      stage16(srcG[0] + k1, &sG[nbG + 0 * 4096 + ldst]);
      stage16(srcG[1] + k1, &sG[nbG + 1 * 4096 + ldst]);
      stage16(srcU[0] + k1, &sU[nbG + 0 * 4096 + ldst]);
      stage16(srcU[1] + k1, &sU[nbG + 1 * 4096 + ldst]);
      VM_WAIT(8);   // previous iter's 8 (buf cur) landed; these 8 stay in flight
    } else {
      VM_WAIT(0);
    }
    SBAR; FENCE;    // all waves' cur stages landed
    bf16x8 af0[8], af1[8], g0[2], g1[2], u0[2], u1[2];
    // ---- kk0 ----
#pragma unroll
    for (int m = 0; m < 8; ++m)
      af0[m] = *(const bf16x8*)&sA[cbA + baseA + m * 1024 + ch0 * 8];
#pragma unroll
    for (int n = 0; n < 2; ++n)
      g0[n] = *(const bf16x8*)&sG[cbG + baseG + n * 1024 + ch0 * 8];
    PRIO_HI;
#pragma unroll
    for (int m = 0; m < 8; ++m)
#pragma unroll
      for (int n = 0; n < 2; ++n)
        accg[m][n] = mfma16(af0[m], g0[n], accg[m][n]);
    PRIO_LO;
#pragma unroll
    for (int n = 0; n < 2; ++n)
      u0[n] = *(const bf16x8*)&sU[cbG + baseG + n * 1024 + ch0 * 8];
    PRIO_HI;
#pragma unroll
    for (int m = 0; m < 8; ++m)
#pragma unroll
      for (int n = 0; n < 2; ++n)
        accu[m][n] = mfma16(af0[m], u0[n], accu[m][n]);
    PRIO_LO;
    // ---- kk1 ----
#pragma unroll
    for (int m = 0; m < 8; ++m)
      af1[m] = *(const bf16x8*)&sA[cbA + baseA + m * 1024 + ch1 * 8];
#pragma unroll
    for (int n = 0; n < 2; ++n)
      g1[n] = *(const bf16x8*)&sG[cbG + baseG + n * 1024 + ch1 * 8];
    PRIO_HI;
#pragma unroll
    for (int m = 0; m < 8; ++m)
#pragma unroll
      for (int n = 0; n < 2; ++n)
        accg[m][n] = mfma16(af1[m], g1[n], accg[m][n]);
    PRIO_LO;
#pragma unroll
    for (int n = 0; n < 2; ++n)
      u1[n] = *(const bf16x8*)&sU[cbG + baseG + n * 1024 + ch1 * 8];
    PRIO_HI;
#pragma unroll
    for (int m = 0; m < 8; ++m)
#pragma unroll
      for (int n = 0; n < 2; ++n)
        accu[m][n] = mfma16(af1[m], u1[n], accu[m][n]);
    PRIO_LO;
    FENCE; SBAR;    // all waves done reading cur before t+1 overwrites it
  }
  // epilogue: SwiGLU, write bf16 P (padded rows junk, never read)
  int rbase = r0 + wr * 128 + l4 * 4;
  int cbase = n0 + wc * 32 + l15;
#pragma unroll
  for (int m = 0; m < 8; ++m) {
#pragma unroll
    for (int r = 0; r < 4; ++r) {
      size_t prow = (size_t)(rbase + m * 16 + r) * IDIM;
#pragma unroll
      for (int n = 0; n < 2; ++n) {
        float g = clamp500(accg[m][n][r]);
        float u = clamp500(accu[m][n][r]);
        float sl = g / (1.f + __expf(-g));
        float p = clamp500(sl * u);
        P[prow + cbase + n * 16] = f2bf(p);
      }
    }
  }
}

// ---------------- GEMM2: slot = weight * clamp(P*Wd^T)  (shared: clamp(clamp(.)*sig)) ----------------
// BM=256, BN=256, BK=64, 8 waves (2x4), same pipelined schedule as gemm1.
__global__ __launch_bounds__(512, 1) void gemm2_kernel(
    const unsigned short* __restrict__ P,
    const unsigned short* __restrict__ wd_all,
    unsigned short* __restrict__ slot,
    const int* __restrict__ meta, const float* __restrict__ lw,
    const float* __restrict__ sgate) {
  int mt = blockIdx.y, nt = blockIdx.x;
  if (mt >= meta[48]) return;
  int ex = meta[64 + mt];
  int r0 = meta[128 + mt];
  extern __shared__ unsigned short lds[];
  unsigned short* sA = lds;          // 2 x 16384 (256x64)
  unsigned short* sB = lds + 32768;  // 2 x 16384 (256x64)
  int tid = threadIdx.x, lane = tid & 63, wv = tid >> 6;
  int wr = wv >> 2, wc = wv & 3;
  int l15 = lane & 15, l4 = lane >> 4;
  int srow = tid >> 3;
  int gch = (tid & 7) ^ (srow & 7);
  int ldst = tid * 8;
  const unsigned short* wd = wd_all + (size_t)ex * EXP_W_ELEMS;
  int n0 = nt * 256;
  const unsigned short* srcA[4];
  const unsigned short* srcB[4];
#pragma unroll
  for (int i = 0; i < 4; ++i) {
    srcA[i] = P + (size_t)(r0 + i * 64 + srow) * IDIM + gch * 8;
    srcB[i] = wd + (size_t)(n0 + i * 64 + srow) * IDIM + gch * 8;
  }
  int ch0 = (0 + l4) ^ (lane & 7);
  int ch1 = (4 + l4) ^ (lane & 7);
  int baseA = (wr * 128 + l15) * 64;
  int baseB = (wc * 64 + l15) * 64;

  f32x4 zero = {0.f, 0.f, 0.f, 0.f};
  f32x4 acc[8][4];
#pragma unroll
  for (int m = 0; m < 8; ++m)
#pragma unroll
    for (int n = 0; n < 4; ++n) acc[m][n] = zero;

  // prologue
#pragma unroll
  for (int i = 0; i < 4; ++i) stage16(srcA[i], &sA[i * 4096 + ldst]);
#pragma unroll
  for (int i = 0; i < 4; ++i) stage16(srcB[i], &sB[i * 4096 + ldst]);

  for (int t = 0; t < 32; ++t) {
    int cur = t & 1, nxt = cur ^ 1;
    int cb = cur * 16384, nb = nxt * 16384;
    if (t < 31) {
      int k1 = (t + 1) * 64;
      stage16(srcA[0] + k1, &sA[nb + 0 * 4096 + ldst]);
      stage16(srcA[1] + k1, &sA[nb + 1 * 4096 + ldst]);
      stage16(srcA[2] + k1, &sA[nb + 2 * 4096 + ldst]);
      stage16(srcA[3] + k1, &sA[nb + 3 * 4096 + ldst]);
      stage16(srcB[0] + k1, &sB[nb + 0 * 4096 + ldst]);
      stage16(srcB[1] + k1, &sB[nb + 1 * 4096 + ldst]);
      stage16(srcB[2] + k1, &sB[nb + 2 * 4096 + ldst]);
      stage16(srcB[3] + k1, &sB[nb + 3 * 4096 + ldst]);
      VM_WAIT(8);
    } else {
      VM_WAIT(0);
    }
    SBAR; FENCE;
    bf16x8 af0[8], af1[8], b0[4], b1[4];
    // ---- kk0 ----
#pragma unroll
    for (int m = 0; m < 8; ++m)
      af0[m] = *(const bf16x8*)&sA[cb + baseA + m * 1024 + ch0 * 8];
#pragma unroll
    for (int n = 0; n < 4; ++n)
      b0[n] = *(const bf16x8*)&sB[cb + baseB + n * 1024 + ch0 * 8];
    PRIO_HI;
#pragma unroll
    for (int m = 0; m < 8; ++m)
#pragma unroll
      for (int n = 0; n < 4; ++n)
        acc[m][n] = mfma16(af0[m], b0[n], acc[m][n]);
    PRIO_LO;
    // ---- kk1 ----
#pragma unroll
    for (int m = 0; m < 8; ++m)
      af1[m] = *(const bf16x8*)&sA[cb + baseA + m * 1024 + ch1 * 8];
#pragma unroll
    for (int n = 0; n < 4; ++n)
      b1[n] = *(const bf16x8*)&sB[cb + baseB + n * 1024 + ch1 * 8];
    PRIO_HI;
#pragma unroll
    for (int m = 0; m < 8; ++m)
#pragma unroll
      for (int n = 0; n < 4; ++n)
        acc[m][n] = mfma16(af1[m], b1[n], acc[m][n]);
    PRIO_LO;
    FENCE; SBAR;
  }
  float gsig = 1.f / (1.f + __expf(-sgate[0]));
  int rbase = r0 + wr * 128 + l4 * 4;
  int cbase = n0 + wc * 64 + l15;
#pragma unroll
  for (int m = 0; m < 8; ++m) {
#pragma unroll
    for (int r = 0; r < 4; ++r) {
      int row = rbase + m * 16 + r;
      float wgt = (ex == 8) ? 1.f : lw[row];
      size_t srow_o = (size_t)row * HDIM;
#pragma unroll
      for (int n = 0; n < 4; ++n) {
        float o = clamp500(acc[m][n][r]);
        float val = (ex == 8) ? clamp500(o * gsig) : wgt * o;
        slot[srow_o + cbase + n * 16] = f2bf(val);
      }
    }
  }
}

// ---------------- combine: final = clamp(slot0 + slot1 + shared) ----------------
__global__ __launch_bounds__(256) void combine_kernel(
    const unsigned short* __restrict__ slot, const int* __restrict__ rowslot,
    const int* __restrict__ meta, float* __restrict__ out) {
  int i = blockIdx.x * 256 + threadIdx.x;  // 4-elem group index
  int t = i >> 8;
  int c = (i & 255) * 4;
  int sb = meta[16 + 8];
  int r0 = rowslot[2 * t], r1 = rowslot[2 * t + 1];
  ushort4 va = *(const ushort4*)(slot + (size_t)r0 * HDIM + c);
  ushort4 vb = *(const ushort4*)(slot + (size_t)r1 * HDIM + c);
  ushort4 vs = *(const ushort4*)(slot + (size_t)(sb + t) * HDIM + c);
  float4 o;
  o.x = clamp500(bf2f(va.x) + bf2f(vb.x) + bf2f(vs.x));
  o.y = clamp500(bf2f(va.y) + bf2f(vb.y) + bf2f(vs.y));
  o.z = clamp500(bf2f(va.z) + bf2f(vb.z) + bf2f(vs.z));
  o.w = clamp500(bf2f(va.w) + bf2f(vb.w) + bf2f(vs.w));
  *(float4*)(out + (size_t)t * HDIM + c) = o;
}

// ---------------- launch ----------------
extern "C" void kernel_launch(void* const* d_in, const int* in_sizes, int n_in,
                              void* d_out, int out_size, void* d_ws, size_t ws_size,
                              hipStream_t stream) {
  const float* x     = (const float*)d_in[0];
  const float* lnw   = (const float*)d_in[1];
  const float* lnb   = (const float*)d_in[2];
  const float* rw    = (const float*)d_in[3];
  const float* wg_f  = (const float*)d_in[4];
  const float* wu_f  = (const float*)d_in[5];
  const float* wd_f  = (const float*)d_in[6];
  const float* swg_f = (const float*)d_in[7];
  const float* swu_f = (const float*)d_in[8];
  const float* swd_f = (const float*)d_in[9];
  const float* sgate = (const float*)d_in[10];
  float* out = (float*)d_out;

  char* ws = (char*)d_ws;
  unsigned short* wgb = (unsigned short*)(ws + OFF_WG);
  unsigned short* wub = (unsigned short*)(ws + OFF_WU);
  unsigned short* wdb = (unsigned short*)(ws + OFF_WD);
  unsigned short* hf  = (unsigned short*)(ws + OFF_HF);
  unsigned short* P   = (unsigned short*)(ws + OFF_P);
  unsigned short* slot = (unsigned short*)(ws + OFF_SLOT);
  int*   top_i   = (int*)(ws + OFF_TOPI);
  float* top_w   = (float*)(ws + OFF_TOPW);
  float* probs   = (float*)(ws + OFF_PROB);
  float* zent    = (float*)(ws + OFF_ZENT);
  int*   meta    = (int*)(ws + OFF_META);
  int*   ltok    = (int*)(ws + OFF_LTOK);
  float* lw      = (float*)(ws + OFF_LW);
  int*   rowslot = (int*)(ws + OFF_ROWS);

  hipFuncSetAttribute((const void*)gemm1_kernel,
                      hipFuncAttributeMaxDynamicSharedMemorySize, 131072);
  hipFuncSetAttribute((const void*)gemm2_kernel,
                      hipFuncAttributeMaxDynamicSharedMemorySize, 131072);

  // router (blocks 0..1023) runs concurrently with fp32->bf16 weight cvt
  // (blocks 1024..3071): latency-bound + BW-bound mix.
  router_cvt_kernel<<<1024 + CVT_BLKS, 256, 0, stream>>>(
      x, lnw, lnb, rw, wg_f, wu_f, wd_f, swg_f, swu_f, swd_f,
      wgb, wub, wdb, hf, top_i, top_w, probs, zent);
  aux_kernel<<<1, 256, 0, stream>>>(top_i, probs, zent, meta, ltok, lw, out + (size_t)TTOK * HDIM);
  scatter_kernel<<<32, 256, 0, stream>>>(top_i, top_w, meta, ltok, lw, rowslot);

  gemm1_kernel<<<dim3(16, MT_MAX), 512, 131072, stream>>>(hf, wgb, wub, P, meta, ltok);
  gemm2_kernel<<<dim3(4, MT_MAX), 512, 131072, stream>>>(P, wdb, slot, meta, lw, sgate);
  combine_kernel<<<TTOK * HDIM / 4 / 256, 256, 0, stream>>>(slot, rowslot, meta, out);
}